// Round 3
// baseline (2720.522 us; speedup 1.0000x reference)
//
#include <hip/hip_runtime.h>
#include <hip/hip_bf16.h>
#include <cstdint>
#include <cstddef>

#define N_NODES 204800
#define N_EDGES 3276800
#define NB 2048
#define NR 100
#define NC 64
#define NH 256
#define KPAD 192          // 64 + 100 padded to 192 (6 x K32 steps)
#define MCHUNK 51200      // 204800 / 4, divisible by 128 and by 100
#define NBKT 400          // buckets of 512 dst nodes

typedef __attribute__((ext_vector_type(8))) short short8;
typedef __attribute__((ext_vector_type(4))) float f32x4;
typedef unsigned int uint32;

__device__ __forceinline__ void gload16(const void* g, void* l) {
    __builtin_amdgcn_global_load_lds(
        (const __attribute__((address_space(1))) uint32_t*)(g),
        (__attribute__((address_space(3))) uint32_t*)(l), 16, 0, 0);
}

__device__ __forceinline__ ushort f2bf(float v) {
    __hip_bfloat16 h = __float2bfloat16(v);
    return *reinterpret_cast<ushort*>(&h);
}

__device__ __forceinline__ uint32 pack2bf(float a, float b) {
    return (uint32)f2bf(a) | ((uint32)f2bf(b) << 16);
}

// ---------------- degree + dinv ----------------

__global__ void k_count(const int* __restrict__ ei, int* __restrict__ cnt) {
    int e = blockIdx.x * 256 + threadIdx.x;
    atomicAdd(&cnt[ei[N_EDGES + e]], 1);
}

__global__ void k_dinv(const int* __restrict__ cnt, float* __restrict__ dinv) {
    int i = blockIdx.x * 256 + threadIdx.x;
    dinv[i] = rsqrtf((float)(cnt[i] + 1));   // +1 self loop
}

// bcnt[b] = sum of cnt over the bucket's 512 nodes
__global__ __launch_bounds__(256) void k_bcnt(const int* __restrict__ cnt,
                                              int* __restrict__ bcnt) {
    __shared__ int red[256];
    int b = blockIdx.x, t = threadIdx.x;
    red[t] = cnt[b * 512 + t] + cnt[b * 512 + 256 + t];
    __syncthreads();
    for (int s = 128; s > 0; s >>= 1) {
        if (t < s) red[t] += red[t + s];
        __syncthreads();
    }
    if (t == 0) bcnt[b] = red[0];
}

// exclusive scan of 400 bucket counts -> boffs, bcur
__global__ void k_bscan(const int* __restrict__ bcnt, int* __restrict__ boffs,
                        int* __restrict__ bcur) {
    __shared__ int tmp[512];
    int t = threadIdx.x;
    int v = (t < NBKT) ? bcnt[t] : 0;
    tmp[t] = v;
    __syncthreads();
    for (int off = 1; off < 512; off <<= 1) {
        int x = 0;
        if (t >= off) x = tmp[t - off];
        __syncthreads();
        tmp[t] += x;
        __syncthreads();
    }
    if (t < NBKT) {
        int o = tmp[t] - v;
        boffs[t] = o;
        bcur[t] = o;
    }
}

// radix partition: part[] gets src | (dlocal<<18), grouped by bucket
__global__ __launch_bounds__(256) void k_bscat(const int* __restrict__ ei,
                                               int* __restrict__ bcur,
                                               uint32* __restrict__ part) {
    __shared__ int hist[NBKT];
    int tid = threadIdx.x;
    for (int i = tid; i < NBKT; i += 256) hist[i] = 0;
    __syncthreads();

    uint32 w[8];
    int bk[8], r[8];
    #pragma unroll 8
    for (int k = 0; k < 8; ++k) {
        int e = blockIdx.x * 2048 + k * 256 + tid;
        int s = ei[e];
        int d = ei[N_EDGES + e];
        int b = d >> 9;
        w[k] = (uint32)s | ((uint32)(d & 511) << 18);
        bk[k] = b;
        r[k] = atomicAdd(&hist[b], 1);
    }
    __syncthreads();
    for (int i = tid; i < NBKT; i += 256) {
        int c = hist[i];
        hist[i] = c ? atomicAdd(&bcur[i], c) : 0;
    }
    __syncthreads();
    #pragma unroll 8
    for (int k = 0; k < 8; ++k)
        part[hist[bk[k]] + r[k]] = w[k];
}

// ssb[i][c] = bf16(dinv[i] * state[i][c]), packed 2 channels per uint
__global__ void k_ssb(const float* __restrict__ state, const float* __restrict__ dinv,
                      uint32* __restrict__ ssb32) {
    int idx = blockIdx.x * 256 + threadIdx.x;     // over N_NODES*32
    int row = idx >> 5;
    float d = dinv[row];
    float2 v = reinterpret_cast<const float2*>(state)[idx];
    ssb32[idx] = pack2bf(v.x * d, v.y * d);
}

// ---------------- bucket-local aggregation ----------------
// 2 blocks per bucket (channel halves); LDS acc[512][34] f32; ds_add_f32
__global__ __launch_bounds__(256) void k_agg(
    const uint32* __restrict__ part, const int* __restrict__ boffs,
    const int* __restrict__ bcnt, const uint32* __restrict__ ssb32,
    const float* __restrict__ dinv, ushort* __restrict__ aggb) {
    __shared__ float acc[512 * 34];
    int tid = threadIdx.x;
    int bkt = blockIdx.x >> 1, phase = blockIdx.x & 1;
    for (int i = tid; i < 512 * 34; i += 256) acc[i] = 0.f;
    __syncthreads();

    int base = boffs[bkt], cntb = bcnt[bkt];
    int wave = tid >> 6, lane = tid & 63;
    int grp = lane >> 4, u = lane & 15;

    for (int i = wave * 4 + grp; i < cntb; i += 16) {
        uint32 ew = part[base + i];                 // broadcast across 16 lanes
        int s = ew & 0x3FFFF;
        int dl = ew >> 18;
        uint32 val = ssb32[(size_t)s * 32 + phase * 16 + u];  // 64B/edge-group
        float f0 = __uint_as_float(val << 16);
        float f1 = __uint_as_float(val & 0xFFFF0000u);
        atomicAdd(&acc[dl * 34 + 2 * u], f0);
        atomicAdd(&acc[dl * 34 + 2 * u + 1], f1);
    }
    __syncthreads();

    uint32* aggu = reinterpret_cast<uint32*>(aggb);
    for (int k = 0; k < 32; ++k) {
        int idx = k * 256 + tid;                    // 8192 = 512 nodes x 16 uints
        int n = idx >> 4, uu = idx & 15;
        float dv = dinv[bkt * 512 + n];
        float f0 = acc[n * 34 + 2 * uu] * dv;
        float f1 = acc[n * 34 + 2 * uu + 1] * dv;
        aggu[(size_t)(bkt * 512 + n) * 32 + phase * 16 + uu] = pack2bf(f0, f1);
    }
}

// ---------------- GCN dense finish: +self, xW, relu, residual -> bf16 ----------------
__global__ __launch_bounds__(256) void k_gcnw(
    const ushort* __restrict__ aggb, const float* __restrict__ state,
    const float* __restrict__ dinv, const float* __restrict__ Wg,
    const float* __restrict__ bg, ushort* __restrict__ xb16) {
    __shared__ float Wl[64 * 64];
    __shared__ float av[4][64];
    int tid = threadIdx.x;
    for (int i = tid; i < 1024; i += 256)
        reinterpret_cast<float4*>(Wl)[i] = reinterpret_cast<const float4*>(Wg)[i];

    int wave = tid >> 6, lane = tid & 63;
    int row = blockIdx.x * 4 + wave;

    float di = dinv[row];
    float st = state[(size_t)row * 64 + lane];
    uint32 ag = aggb[(size_t)row * 64 + lane];
    float a = __uint_as_float(ag << 16) + di * di * st;   // edges + self loop

    __syncthreads();            // Wl ready
    av[wave][lane] = a;
    __syncthreads();            // av ready

    float r = bg[lane];
    #pragma unroll
    for (int c4 = 0; c4 < 64; c4 += 4) {
        float4 a4 = *reinterpret_cast<const float4*>(&av[wave][c4]);
        r += a4.x * Wl[(c4 + 0) * 64 + lane];
        r += a4.y * Wl[(c4 + 1) * 64 + lane];
        r += a4.z * Wl[(c4 + 2) * 64 + lane];
        r += a4.w * Wl[(c4 + 3) * 64 + lane];
    }
    xb16[(size_t)row * 64 + lane] = f2bf(fmaxf(r, 0.f) + st);
}

// ---------------- pack kernels ----------------

// A[lr][0:64]=xb16, [64:164]=action, [164:192]=0 ; one chunk of rows
__global__ __launch_bounds__(256) void k_packA(
    const ushort* __restrict__ xb16, const float* __restrict__ action,
    ushort* __restrict__ Ap, int grow0) {
    int tid = threadIdx.x;
    int w = tid >> 6, lane = tid & 63;
    int lr = blockIdx.x * 4 + w;
    int gr = grow0 + lr;
    int b = gr / 100, r = gr % 100;
    const float* ab = action + (size_t)b * 10000 + (size_t)r * 100;
    ushort v0 = xb16[(size_t)gr * 64 + lane];
    float v1 = ab[lane];
    float v2 = (lane < 36) ? ab[64 + lane] : 0.f;
    ushort* row = Ap + (size_t)lr * KPAD;
    row[lane] = v0;
    row[64 + lane] = f2bf(v1);
    row[128 + lane] = f2bf(v2);
}

// W1t[j][k] = W1[k][j] (k<164, else 0), W2t[j][k] = W2[k][j]; bf16
__global__ void k_packW(const float* __restrict__ W1, const float* __restrict__ W2,
                        ushort* __restrict__ W1t, ushort* __restrict__ W2t) {
    int t = blockIdx.x * 256 + threadIdx.x;
    if (t < 256 * KPAD) {
        int j = t / KPAD, k = t % KPAD;
        W1t[t] = (k < NC + NR) ? f2bf(W1[(size_t)k * NH + j]) : (ushort)0;
    } else {
        int t2 = t - 256 * KPAD;
        if (t2 < 256 * 256) {
            int j = t2 / 256, k = t2 % 256;
            W2t[t2] = f2bf(W2[(size_t)k * NH + j]);
        }
    }
}

// ---------------- MFMA GEMMs (128x128 tile, BK=32) ----------------

__global__ __launch_bounds__(256) void k_gemm1(
    const ushort* __restrict__ Ap, const ushort* __restrict__ W1t,
    const float* __restrict__ b1, ushort* __restrict__ H1) {
    __shared__ __align__(16) ushort Asm[128 * 32];
    __shared__ __align__(16) ushort Bsm[128 * 32];
    int tid = threadIdx.x;
    int w = tid >> 6, lane = tid & 63;
    int m0 = (blockIdx.x >> 1) * 128;
    int n0 = (blockIdx.x & 1) * 128;
    int wm = w >> 1, wn = w & 1;
    int srow = lane >> 2, seg = lane & 3;

    f32x4 acc[4][4] = {};

    for (int kt = 0; kt < 6; ++kt) {
        int k0 = kt * 32;
        #pragma unroll
        for (int i = 0; i < 2; ++i) {
            int rr = (w * 2 + i) * 16 + srow;
            gload16(Ap + (size_t)(m0 + rr) * KPAD + k0 + seg * 8,
                    (char*)Asm + (w * 2 + i) * 1024 + lane * 16);
            gload16(W1t + (size_t)(n0 + rr) * KPAD + k0 + seg * 8,
                    (char*)Bsm + (w * 2 + i) * 1024 + lane * 16);
        }
        __syncthreads();
        short8 af[4], bfr[4];
        #pragma unroll
        for (int mt = 0; mt < 4; ++mt)
            af[mt] = *(const short8*)((const char*)Asm +
                     (wm * 64 + mt * 16 + (lane & 15)) * 64 + (lane >> 4) * 16);
        #pragma unroll
        for (int nt = 0; nt < 4; ++nt)
            bfr[nt] = *(const short8*)((const char*)Bsm +
                      (wn * 64 + nt * 16 + (lane & 15)) * 64 + (lane >> 4) * 16);
        #pragma unroll
        for (int mt = 0; mt < 4; ++mt)
            #pragma unroll
            for (int nt = 0; nt < 4; ++nt)
                acc[mt][nt] = __builtin_amdgcn_mfma_f32_16x16x32_bf16(
                    af[mt], bfr[nt], acc[mt][nt], 0, 0, 0);
        __syncthreads();
    }

    #pragma unroll
    for (int nt = 0; nt < 4; ++nt) {
        int col = n0 + wn * 64 + nt * 16 + (lane & 15);
        float bias = b1[col];
        #pragma unroll
        for (int mt = 0; mt < 4; ++mt) {
            #pragma unroll
            for (int r = 0; r < 4; ++r) {
                int row = m0 + wm * 64 + mt * 16 + (lane >> 4) * 4 + r;
                float v = acc[mt][nt][r] + bias;
                H1[(size_t)row * 256 + col] = f2bf(fmaxf(v, 0.f));
            }
        }
    }
}

__global__ __launch_bounds__(256) void k_gemm2(
    const ushort* __restrict__ H1, const ushort* __restrict__ W2t,
    const float* __restrict__ b2, const float* __restrict__ W3,
    float* __restrict__ out, int grow0) {
    __shared__ __align__(16) ushort Asm[128 * 32];
    __shared__ __align__(16) ushort Bsm[128 * 32];
    int tid = threadIdx.x;
    int w = tid >> 6, lane = tid & 63;
    int m0 = (blockIdx.x >> 1) * 128;
    int n0 = (blockIdx.x & 1) * 128;
    int wm = w >> 1, wn = w & 1;
    int srow = lane >> 2, seg = lane & 3;

    f32x4 acc[4][4] = {};

    for (int kt = 0; kt < 8; ++kt) {
        int k0 = kt * 32;
        #pragma unroll
        for (int i = 0; i < 2; ++i) {
            int rr = (w * 2 + i) * 16 + srow;
            gload16(H1 + (size_t)(m0 + rr) * 256 + k0 + seg * 8,
                    (char*)Asm + (w * 2 + i) * 1024 + lane * 16);
            gload16(W2t + (size_t)(n0 + rr) * 256 + k0 + seg * 8,
                    (char*)Bsm + (w * 2 + i) * 1024 + lane * 16);
        }
        __syncthreads();
        short8 af[4], bfr[4];
        #pragma unroll
        for (int mt = 0; mt < 4; ++mt)
            af[mt] = *(const short8*)((const char*)Asm +
                     (wm * 64 + mt * 16 + (lane & 15)) * 64 + (lane >> 4) * 16);
        #pragma unroll
        for (int nt = 0; nt < 4; ++nt)
            bfr[nt] = *(const short8*)((const char*)Bsm +
                      (wn * 64 + nt * 16 + (lane & 15)) * 64 + (lane >> 4) * 16);
        #pragma unroll
        for (int mt = 0; mt < 4; ++mt)
            #pragma unroll
            for (int nt = 0; nt < 4; ++nt)
                acc[mt][nt] = __builtin_amdgcn_mfma_f32_16x16x32_bf16(
                    af[mt], bfr[nt], acc[mt][nt], 0, 0, 0);
        __syncthreads();
    }

    float p[4][4];
    #pragma unroll
    for (int mt = 0; mt < 4; ++mt)
        #pragma unroll
        for (int r = 0; r < 4; ++r) p[mt][r] = 0.f;

    #pragma unroll
    for (int nt = 0; nt < 4; ++nt) {
        int col = n0 + wn * 64 + nt * 16 + (lane & 15);
        float bias = b2[col];
        float w3v = W3[col];
        #pragma unroll
        for (int mt = 0; mt < 4; ++mt) {
            #pragma unroll
            for (int r = 0; r < 4; ++r) {
                float v = fmaxf(acc[mt][nt][r] + bias, 0.f);
                p[mt][r] += v * w3v;
            }
        }
    }

    #pragma unroll
    for (int mt = 0; mt < 4; ++mt) {
        #pragma unroll
        for (int r = 0; r < 4; ++r) {
            float v = p[mt][r];
            v += __shfl_xor(v, 1);
            v += __shfl_xor(v, 2);
            v += __shfl_xor(v, 4);
            v += __shfl_xor(v, 8);
            if ((lane & 15) == 0) {
                int row = grow0 + m0 + wm * 64 + mt * 16 + (lane >> 4) * 4 + r;
                atomicAdd(&out[row / 100], v);
            }
        }
    }
}

__global__ void k_init_out(float* __restrict__ out, const float* __restrict__ b3) {
    int i = blockIdx.x * 256 + threadIdx.x;
    out[i] = b3[0];
}

// ---------------- launch ----------------

extern "C" void kernel_launch(void* const* d_in, const int* in_sizes, int n_in,
                              void* d_out, int out_size, void* d_ws, size_t ws_size,
                              hipStream_t stream) {
    const float* state  = (const float*)d_in[0];
    const int*   ei     = (const int*)d_in[1];
    const float* action = (const float*)d_in[2];
    const float* Wg     = (const float*)d_in[3];
    const float* bg     = (const float*)d_in[4];
    const float* W1     = (const float*)d_in[5];
    const float* b1     = (const float*)d_in[6];
    const float* W2     = (const float*)d_in[7];
    const float* b2     = (const float*)d_in[8];
    const float* W3     = (const float*)d_in[9];
    const float* b3     = (const float*)d_in[10];
    float* out = (float*)d_out;

    char* ws = (char*)d_ws;
    // Overlaid slots (live ranges):
    //   [0, 19.7MB)   part (bscat..agg)  then Ap chunk (packA(c)..gemm1(c))
    //   [19.7, 45.9)  ssb (ssb..agg)     then xb16 (gcnw..packA(last))
    //   [45.9, 72.1)  aggb (agg..gcnw)   then H1 chunk (gemm1(c)..gemm2(c))
    uint32* part  = (uint32*)(ws + 0);                 // 13,107,200 used of 19,660,800
    ushort* Ap    = (ushort*)(ws + 0);
    uint32* ssb32 = (uint32*)(ws + 19660800);          // 26,214,400
    ushort* xb16  = (ushort*)(ws + 19660800);
    ushort* aggb  = (ushort*)(ws + 45875200);          // 26,214,400
    ushort* H1    = (ushort*)(ws + 45875200);
    int*   cnt    = (int*)  (ws + 72089600);           //    819,200
    float* dinv   = (float*)(ws + 72908800);           //    819,200
    int*   bcnt   = (int*)  (ws + 73728000);           //      1,600
    int*   boffs  = (int*)  (ws + 73729600);           //      1,600
    int*   bcur   = (int*)  (ws + 73731200);           //      1,600
    ushort* W1t   = (ushort*)(ws + 73732800);          //     98,304
    ushort* W2t   = (ushort*)(ws + 73831104);          //    131,072 -> end 73,962,176

    hipMemsetAsync(cnt, 0, N_NODES * sizeof(int), stream);
    k_init_out<<<NB / 256, 256, 0, stream>>>(out, b3);

    k_count<<<N_EDGES / 256, 256, 0, stream>>>(ei, cnt);
    k_dinv<<<N_NODES / 256, 256, 0, stream>>>(cnt, dinv);
    k_bcnt<<<NBKT, 256, 0, stream>>>(cnt, bcnt);
    k_bscan<<<1, 512, 0, stream>>>(bcnt, boffs, bcur);
    k_bscat<<<N_EDGES / 2048, 256, 0, stream>>>(ei, bcur, part);
    k_ssb<<<(N_NODES * 32) / 256, 256, 0, stream>>>(state, dinv, ssb32);
    k_agg<<<NBKT * 2, 256, 0, stream>>>(part, boffs, bcnt, ssb32, dinv, aggb);
    k_gcnw<<<N_NODES / 4, 256, 0, stream>>>(aggb, state, dinv, Wg, bg, xb16);
    k_packW<<<(256 * KPAD + 256 * 256 + 255) / 256, 256, 0, stream>>>(W1, W2, W1t, W2t);

    for (int c = 0; c < 4; ++c) {
        int grow0 = c * MCHUNK;
        k_packA<<<MCHUNK / 4, 256, 0, stream>>>(xb16, action, Ap, grow0);
        k_gemm1<<<(MCHUNK / 128) * 2, 256, 0, stream>>>(Ap, W1t, b1, H1);
        k_gemm2<<<(MCHUNK / 128) * 2, 256, 0, stream>>>(H1, W2t, b2, W3, out, grow0);
    }
}

// Round 4
// 1410.095 us; speedup vs baseline: 1.9293x; 1.9293x over previous
//
#include <hip/hip_runtime.h>
#include <hip/hip_bf16.h>
#include <cstdint>
#include <cstddef>

#define N_NODES 204800
#define N_EDGES 3276800
#define NB 2048
#define NR 100
#define NC 64
#define NH 256
#define KPAD 192          // 64 + 100 padded to 192 (6 x K32 steps)
#define MCHUNK 51200      // 204800 / 4, divisible by 128 and by 100
#define NBKT 400          // buckets of 512 dst nodes

typedef __attribute__((ext_vector_type(8))) short short8;
typedef __attribute__((ext_vector_type(4))) float f32x4;
typedef unsigned int uint32;

__device__ __forceinline__ void gload16(const void* g, void* l) {
    __builtin_amdgcn_global_load_lds(
        (const __attribute__((address_space(1))) uint32_t*)(g),
        (__attribute__((address_space(3))) uint32_t*)(l), 16, 0, 0);
}

__device__ __forceinline__ ushort f2bf(float v) {
    __hip_bfloat16 h = __float2bfloat16(v);
    return *reinterpret_cast<ushort*>(&h);
}

__device__ __forceinline__ uint32 pack2bf(float a, float b) {
    return (uint32)f2bf(a) | ((uint32)f2bf(b) << 16);
}

__device__ __forceinline__ float bfext(uint32 v, int odd) {
    return __uint_as_float(odd ? (v & 0xFFFF0000u) : (v << 16));
}

// ---------------- bucket histogram (replaces k_count + scans) ----------------

__global__ __launch_bounds__(256) void k_bhist(const int* __restrict__ ei,
                                               int* __restrict__ bcnt) {
    __shared__ int h[NBKT];
    int t = threadIdx.x;
    for (int i = t; i < NBKT; i += 256) h[i] = 0;
    __syncthreads();
    #pragma unroll 8
    for (int k = 0; k < 8; ++k) {
        int e = blockIdx.x * 2048 + k * 256 + t;
        atomicAdd(&h[ei[N_EDGES + e] >> 9], 1);
    }
    __syncthreads();
    for (int i = t; i < NBKT; i += 256)
        if (h[i]) atomicAdd(&bcnt[i], h[i]);
}

// exclusive scan of 400 bucket counts -> boffs, bcur
__global__ void k_bscan(const int* __restrict__ bcnt, int* __restrict__ boffs,
                        int* __restrict__ bcur) {
    __shared__ int tmp[512];
    int t = threadIdx.x;
    int v = (t < NBKT) ? bcnt[t] : 0;
    tmp[t] = v;
    __syncthreads();
    for (int off = 1; off < 512; off <<= 1) {
        int x = 0;
        if (t >= off) x = tmp[t - off];
        __syncthreads();
        tmp[t] += x;
        __syncthreads();
    }
    if (t < NBKT) {
        int o = tmp[t] - v;
        boffs[t] = o;
        bcur[t] = o;
    }
}

// radix partition: part[] gets src | (dlocal<<18), grouped by bucket
__global__ __launch_bounds__(256) void k_bscat(const int* __restrict__ ei,
                                               int* __restrict__ bcur,
                                               uint32* __restrict__ part) {
    __shared__ int hist[NBKT];
    int tid = threadIdx.x;
    for (int i = tid; i < NBKT; i += 256) hist[i] = 0;
    __syncthreads();

    uint32 w[8];
    int bk[8], r[8];
    #pragma unroll 8
    for (int k = 0; k < 8; ++k) {
        int e = blockIdx.x * 2048 + k * 256 + tid;
        int s = ei[e];
        int d = ei[N_EDGES + e];
        int b = d >> 9;
        w[k] = (uint32)s | ((uint32)(d & 511) << 18);
        bk[k] = b;
        r[k] = atomicAdd(&hist[b], 1);
    }
    __syncthreads();
    for (int i = tid; i < NBKT; i += 256) {
        int c = hist[i];
        hist[i] = c ? atomicAdd(&bcur[i], c) : 0;
    }
    __syncthreads();
    #pragma unroll 8
    for (int k = 0; k < 8; ++k)
        part[hist[bk[k]] + r[k]] = w[k];
}

// per-bucket counting sort -> CSR ; also emits cnt/offs/dinv
__global__ __launch_bounds__(512) void k_sortb(
    const uint32* __restrict__ part, const int* __restrict__ boffs,
    const int* __restrict__ bcnt, int* __restrict__ csr,
    int* __restrict__ cnt, int* __restrict__ offs, float* __restrict__ dinv) {
    __shared__ int h[512];
    __shared__ int cur[512];
    int b = blockIdx.x, t = threadIdx.x;
    h[t] = 0;
    __syncthreads();
    int base = boffs[b], n = bcnt[b];
    for (int i = t; i < n; i += 512)
        atomicAdd(&h[part[base + i] >> 18], 1);
    __syncthreads();
    int v = h[t];
    int node = b * 512 + t;
    cnt[node] = v;
    dinv[node] = rsqrtf((float)(v + 1));        // +1 self loop
    __syncthreads();
    for (int off = 1; off < 512; off <<= 1) {   // Hillis-Steele inclusive scan on h
        int x = 0;
        if (t >= off) x = h[t - off];
        __syncthreads();
        h[t] += x;
        __syncthreads();
    }
    int excl = h[t] - v;
    offs[node] = base + excl;                   // global CSR offset
    cur[t] = excl;
    __syncthreads();
    for (int i = t; i < n; i += 512) {
        uint32 ew = part[base + i];
        int dl = ew >> 18;
        int pos = atomicAdd(&cur[dl], 1);
        csr[base + pos] = (int)(ew & 0x3FFFF);  // writes land in a ~34KB window -> L2
    }
}

// ssb[i][c] = bf16(dinv[i] * state[i][c]), packed 2 channels per uint
__global__ void k_ssb(const float* __restrict__ state, const float* __restrict__ dinv,
                      uint32* __restrict__ ssb32) {
    int idx = blockIdx.x * 256 + threadIdx.x;     // over N_NODES*32
    int row = idx >> 5;
    float d = dinv[row];
    float2 v = reinterpret_cast<const float2*>(state)[idx];
    ssb32[idx] = pack2bf(v.x * d, v.y * d);
}

// ---------------- GCN pull-gather (bf16) + 64x64 GEMM + relu + residual ----------------
// one wave per node row; lane = channel; high occupancy + 4-way ILP
__global__ __launch_bounds__(256) void k_gcn(
    const uint32* __restrict__ ssb32, const float* __restrict__ state,
    const int* __restrict__ csr, const int* __restrict__ offs,
    const int* __restrict__ cnt, const float* __restrict__ dinv,
    const float* __restrict__ Wg, const float* __restrict__ bg,
    ushort* __restrict__ xb16) {
    __shared__ float Wl[64 * 64];
    __shared__ float av[4][64];
    int tid = threadIdx.x;
    for (int i = tid; i < 1024; i += 256)
        reinterpret_cast<float4*>(Wl)[i] = reinterpret_cast<const float4*>(Wg)[i];

    int wave = tid >> 6, lane = tid & 63;
    int row = blockIdx.x * 4 + wave;
    int c2 = lane >> 1, odd = lane & 1;

    float di = dinv[row];
    float st = state[(size_t)row * 64 + lane];
    float a0 = 0.f, a1 = 0.f, a2 = 0.f, a3 = 0.f;
    int s0 = offs[row], c = cnt[row];
    int e = 0;
    for (; e + 4 <= c; e += 4) {
        int sa = csr[s0 + e + 0];
        int sb = csr[s0 + e + 1];
        int sc = csr[s0 + e + 2];
        int sd = csr[s0 + e + 3];
        uint32 va = ssb32[(size_t)sa * 32 + c2];   // 128B/edge, lanes pair-share
        uint32 vb = ssb32[(size_t)sb * 32 + c2];
        uint32 vc = ssb32[(size_t)sc * 32 + c2];
        uint32 vd = ssb32[(size_t)sd * 32 + c2];
        a0 += bfext(va, odd);
        a1 += bfext(vb, odd);
        a2 += bfext(vc, odd);
        a3 += bfext(vd, odd);
    }
    for (; e < c; ++e) {
        int s = csr[s0 + e];
        a0 += bfext(ssb32[(size_t)s * 32 + c2], odd);
    }
    float a = ((a0 + a1) + (a2 + a3)) * di + di * di * st;   // edges + self loop

    __syncthreads();            // Wl ready
    av[wave][lane] = a;
    __syncthreads();            // av ready

    float r = bg[lane];
    #pragma unroll
    for (int c4 = 0; c4 < 64; c4 += 4) {
        float4 a4 = *reinterpret_cast<const float4*>(&av[wave][c4]);
        r += a4.x * Wl[(c4 + 0) * 64 + lane];
        r += a4.y * Wl[(c4 + 1) * 64 + lane];
        r += a4.z * Wl[(c4 + 2) * 64 + lane];
        r += a4.w * Wl[(c4 + 3) * 64 + lane];
    }
    xb16[(size_t)row * 64 + lane] = f2bf(fmaxf(r, 0.f) + st);
}

// ---------------- pack kernels ----------------

__global__ __launch_bounds__(256) void k_packA(
    const ushort* __restrict__ xb16, const float* __restrict__ action,
    ushort* __restrict__ Ap, int grow0) {
    int tid = threadIdx.x;
    int w = tid >> 6, lane = tid & 63;
    int lr = blockIdx.x * 4 + w;
    int gr = grow0 + lr;
    int b = gr / 100, r = gr % 100;
    const float* ab = action + (size_t)b * 10000 + (size_t)r * 100;
    ushort v0 = xb16[(size_t)gr * 64 + lane];
    float v1 = ab[lane];
    float v2 = (lane < 36) ? ab[64 + lane] : 0.f;
    ushort* row = Ap + (size_t)lr * KPAD;
    row[lane] = v0;
    row[64 + lane] = f2bf(v1);
    row[128 + lane] = f2bf(v2);
}

__global__ void k_packW(const float* __restrict__ W1, const float* __restrict__ W2,
                        ushort* __restrict__ W1t, ushort* __restrict__ W2t) {
    int t = blockIdx.x * 256 + threadIdx.x;
    if (t < 256 * KPAD) {
        int j = t / KPAD, k = t % KPAD;
        W1t[t] = (k < NC + NR) ? f2bf(W1[(size_t)k * NH + j]) : (ushort)0;
    } else {
        int t2 = t - 256 * KPAD;
        if (t2 < 256 * 256) {
            int j = t2 / 256, k = t2 % 256;
            W2t[t2] = f2bf(W2[(size_t)k * NH + j]);
        }
    }
}

// ---------------- MFMA GEMMs (128x128 tile, BK=32) ----------------

__global__ __launch_bounds__(256) void k_gemm1(
    const ushort* __restrict__ Ap, const ushort* __restrict__ W1t,
    const float* __restrict__ b1, ushort* __restrict__ H1) {
    __shared__ __align__(16) ushort Asm[128 * 32];
    __shared__ __align__(16) ushort Bsm[128 * 32];
    int tid = threadIdx.x;
    int w = tid >> 6, lane = tid & 63;
    int m0 = (blockIdx.x >> 1) * 128;
    int n0 = (blockIdx.x & 1) * 128;
    int wm = w >> 1, wn = w & 1;
    int srow = lane >> 2, seg = lane & 3;

    f32x4 acc[4][4] = {};

    for (int kt = 0; kt < 6; ++kt) {
        int k0 = kt * 32;
        #pragma unroll
        for (int i = 0; i < 2; ++i) {
            int rr = (w * 2 + i) * 16 + srow;
            gload16(Ap + (size_t)(m0 + rr) * KPAD + k0 + seg * 8,
                    (char*)Asm + (w * 2 + i) * 1024 + lane * 16);
            gload16(W1t + (size_t)(n0 + rr) * KPAD + k0 + seg * 8,
                    (char*)Bsm + (w * 2 + i) * 1024 + lane * 16);
        }
        __syncthreads();
        short8 af[4], bfr[4];
        #pragma unroll
        for (int mt = 0; mt < 4; ++mt)
            af[mt] = *(const short8*)((const char*)Asm +
                     (wm * 64 + mt * 16 + (lane & 15)) * 64 + (lane >> 4) * 16);
        #pragma unroll
        for (int nt = 0; nt < 4; ++nt)
            bfr[nt] = *(const short8*)((const char*)Bsm +
                      (wn * 64 + nt * 16 + (lane & 15)) * 64 + (lane >> 4) * 16);
        #pragma unroll
        for (int mt = 0; mt < 4; ++mt)
            #pragma unroll
            for (int nt = 0; nt < 4; ++nt)
                acc[mt][nt] = __builtin_amdgcn_mfma_f32_16x16x32_bf16(
                    af[mt], bfr[nt], acc[mt][nt], 0, 0, 0);
        __syncthreads();
    }

    #pragma unroll
    for (int nt = 0; nt < 4; ++nt) {
        int col = n0 + wn * 64 + nt * 16 + (lane & 15);
        float bias = b1[col];
        #pragma unroll
        for (int mt = 0; mt < 4; ++mt) {
            #pragma unroll
            for (int r = 0; r < 4; ++r) {
                int row = m0 + wm * 64 + mt * 16 + (lane >> 4) * 4 + r;
                float v = acc[mt][nt][r] + bias;
                H1[(size_t)row * 256 + col] = f2bf(fmaxf(v, 0.f));
            }
        }
    }
}

__global__ __launch_bounds__(256) void k_gemm2(
    const ushort* __restrict__ H1, const ushort* __restrict__ W2t,
    const float* __restrict__ b2, const float* __restrict__ W3,
    float* __restrict__ out, int grow0) {
    __shared__ __align__(16) ushort Asm[128 * 32];
    __shared__ __align__(16) ushort Bsm[128 * 32];
    int tid = threadIdx.x;
    int w = tid >> 6, lane = tid & 63;
    int m0 = (blockIdx.x >> 1) * 128;
    int n0 = (blockIdx.x & 1) * 128;
    int wm = w >> 1, wn = w & 1;
    int srow = lane >> 2, seg = lane & 3;

    f32x4 acc[4][4] = {};

    for (int kt = 0; kt < 8; ++kt) {
        int k0 = kt * 32;
        #pragma unroll
        for (int i = 0; i < 2; ++i) {
            int rr = (w * 2 + i) * 16 + srow;
            gload16(H1 + (size_t)(m0 + rr) * 256 + k0 + seg * 8,
                    (char*)Asm + (w * 2 + i) * 1024 + lane * 16);
            gload16(W2t + (size_t)(n0 + rr) * 256 + k0 + seg * 8,
                    (char*)Bsm + (w * 2 + i) * 1024 + lane * 16);
        }
        __syncthreads();
        short8 af[4], bfr[4];
        #pragma unroll
        for (int mt = 0; mt < 4; ++mt)
            af[mt] = *(const short8*)((const char*)Asm +
                     (wm * 64 + mt * 16 + (lane & 15)) * 64 + (lane >> 4) * 16);
        #pragma unroll
        for (int nt = 0; nt < 4; ++nt)
            bfr[nt] = *(const short8*)((const char*)Bsm +
                      (wn * 64 + nt * 16 + (lane & 15)) * 64 + (lane >> 4) * 16);
        #pragma unroll
        for (int mt = 0; mt < 4; ++mt)
            #pragma unroll
            for (int nt = 0; nt < 4; ++nt)
                acc[mt][nt] = __builtin_amdgcn_mfma_f32_16x16x32_bf16(
                    af[mt], bfr[nt], acc[mt][nt], 0, 0, 0);
        __syncthreads();
    }

    float p[4][4];
    #pragma unroll
    for (int mt = 0; mt < 4; ++mt)
        #pragma unroll
        for (int r = 0; r < 4; ++r) p[mt][r] = 0.f;

    #pragma unroll
    for (int nt = 0; nt < 4; ++nt) {
        int col = n0 + wn * 64 + nt * 16 + (lane & 15);
        float bias = b2[col];
        float w3v = W3[col];
        #pragma unroll
        for (int mt = 0; mt < 4; ++mt) {
            #pragma unroll
            for (int r = 0; r < 4; ++r) {
                float v = fmaxf(acc[mt][nt][r] + bias, 0.f);
                p[mt][r] += v * w3v;
            }
        }
    }

    #pragma unroll
    for (int mt = 0; mt < 4; ++mt) {
        #pragma unroll
        for (int r = 0; r < 4; ++r) {
            float v = p[mt][r];
            v += __shfl_xor(v, 1);
            v += __shfl_xor(v, 2);
            v += __shfl_xor(v, 4);
            v += __shfl_xor(v, 8);
            if ((lane & 15) == 0) {
                int row = grow0 + m0 + wm * 64 + mt * 16 + (lane >> 4) * 4 + r;
                atomicAdd(&out[row / 100], v);
            }
        }
    }
}

__global__ void k_init_out(float* __restrict__ out, const float* __restrict__ b3) {
    int i = blockIdx.x * 256 + threadIdx.x;
    out[i] = b3[0];
}

// ---------------- launch ----------------

extern "C" void kernel_launch(void* const* d_in, const int* in_sizes, int n_in,
                              void* d_out, int out_size, void* d_ws, size_t ws_size,
                              hipStream_t stream) {
    const float* state  = (const float*)d_in[0];
    const int*   ei     = (const int*)d_in[1];
    const float* action = (const float*)d_in[2];
    const float* Wg     = (const float*)d_in[3];
    const float* bg     = (const float*)d_in[4];
    const float* W1     = (const float*)d_in[5];
    const float* b1     = (const float*)d_in[6];
    const float* W2     = (const float*)d_in[7];
    const float* b2     = (const float*)d_in[8];
    const float* W3     = (const float*)d_in[9];
    const float* b3     = (const float*)d_in[10];
    float* out = (float*)d_out;

    char* ws = (char*)d_ws;
    // Overlays (live ranges):
    //   [0, 19.7MB)     part (bscat..sortb)      then Ap chunk (packA..gemm1)
    //   [19.7, 45.9MB)  ssb32 (ssb..gcn)         then H1 chunk (gemm1..gemm2)
    //   [45.9, 72.1MB)  xb16 (gcn..packA last)
    uint32* part  = (uint32*)(ws + 0);                 // 13,107,200
    ushort* Ap    = (ushort*)(ws + 0);                 // 19,660,800
    uint32* ssb32 = (uint32*)(ws + 19660800);          // 26,214,400
    ushort* H1    = (ushort*)(ws + 19660800);          // 26,214,400
    ushort* xb16  = (ushort*)(ws + 45875200);          // 26,214,400
    int*   csr    = (int*)  (ws + 72089600);           // 13,107,200
    int*   cnt    = (int*)  (ws + 85196800);           //    819,200
    int*   offs   = (int*)  (ws + 86016000);           //    819,200
    float* dinv   = (float*)(ws + 86835200);           //    819,200
    int*   bcnt   = (int*)  (ws + 87654400);           //      1,600
    int*   boffs  = (int*)  (ws + 87656000);           //      1,600
    int*   bcur   = (int*)  (ws + 87657600);           //      1,600
    ushort* W1t   = (ushort*)(ws + 87659200);          //     98,304
    ushort* W2t   = (ushort*)(ws + 87757504);          //    131,072 -> end 87,888,576

    hipMemsetAsync(bcnt, 0, NBKT * sizeof(int), stream);
    k_init_out<<<NB / 256, 256, 0, stream>>>(out, b3);

    k_bhist<<<N_EDGES / 2048, 256, 0, stream>>>(ei, bcnt);
    k_bscan<<<1, 512, 0, stream>>>(bcnt, boffs, bcur);
    k_bscat<<<N_EDGES / 2048, 256, 0, stream>>>(ei, bcur, part);
    k_sortb<<<NBKT, 512, 0, stream>>>(part, boffs, bcnt, csr, cnt, offs, dinv);
    k_ssb<<<(N_NODES * 32) / 256, 256, 0, stream>>>(state, dinv, ssb32);
    k_gcn<<<N_NODES / 4, 256, 0, stream>>>(ssb32, state, csr, offs, cnt, dinv, Wg, bg, xb16);
    k_packW<<<(256 * KPAD + 256 * 256 + 255) / 256, 256, 0, stream>>>(W1, W2, W1t, W2t);

    for (int c = 0; c < 4; ++c) {
        int grow0 = c * MCHUNK;
        k_packA<<<MCHUNK / 4, 256, 0, stream>>>(xb16, action, Ap, grow0);
        k_gemm1<<<(MCHUNK / 128) * 2, 256, 0, stream>>>(Ap, W1t, b1, H1);
        k_gemm2<<<(MCHUNK / 128) * 2, 256, 0, stream>>>(H1, W2t, b2, W3, out, grow0);
    }
}

// Round 5
// 469.565 us; speedup vs baseline: 5.7937x; 3.0030x over previous
//
#include <hip/hip_runtime.h>
#include <hip/hip_bf16.h>
#include <cstdint>
#include <cstddef>

#define N_NODES 204800
#define N_EDGES 3276800
#define NB 2048
#define NR 100
#define NC 64
#define NH 256
#define KPAD 192          // 64 + 100 padded to 192 (6 x K32 steps)
#define MCHUNK 102400     // 204800 / 2, divisible by 64 and by 100
#define NBKT 400          // buckets of 512 dst nodes
#define H1P 264           // h1 LDS pitch (bf16): 528B rows -> bank-spread frag reads

typedef __attribute__((ext_vector_type(8))) short short8;
typedef __attribute__((ext_vector_type(4))) float f32x4;
typedef unsigned int uint32;

__device__ __forceinline__ void gload16(const void* g, void* l) {
    __builtin_amdgcn_global_load_lds(
        (const __attribute__((address_space(1))) uint32_t*)(g),
        (__attribute__((address_space(3))) uint32_t*)(l), 16, 0, 0);
}

__device__ __forceinline__ ushort f2bf(float v) {
    __hip_bfloat16 h = __float2bfloat16(v);
    return *reinterpret_cast<ushort*>(&h);
}

__device__ __forceinline__ uint32 pack2bf(float a, float b) {
    return (uint32)f2bf(a) | ((uint32)f2bf(b) << 16);
}

__device__ __forceinline__ float bfext(uint32 v, int odd) {
    return __uint_as_float(odd ? (v & 0xFFFF0000u) : (v << 16));
}

// ---------------- bucket histogram ----------------

__global__ __launch_bounds__(256) void k_bhist(const int* __restrict__ ei,
                                               int* __restrict__ bcnt) {
    __shared__ int h[NBKT];
    int t = threadIdx.x;
    for (int i = t; i < NBKT; i += 256) h[i] = 0;
    __syncthreads();
    #pragma unroll 8
    for (int k = 0; k < 8; ++k) {
        int e = blockIdx.x * 2048 + k * 256 + t;
        atomicAdd(&h[ei[N_EDGES + e] >> 9], 1);
    }
    __syncthreads();
    for (int i = t; i < NBKT; i += 256)
        if (h[i]) atomicAdd(&bcnt[i], h[i]);
}

__global__ void k_bscan(const int* __restrict__ bcnt, int* __restrict__ boffs,
                        int* __restrict__ bcur) {
    __shared__ int tmp[512];
    int t = threadIdx.x;
    int v = (t < NBKT) ? bcnt[t] : 0;
    tmp[t] = v;
    __syncthreads();
    for (int off = 1; off < 512; off <<= 1) {
        int x = 0;
        if (t >= off) x = tmp[t - off];
        __syncthreads();
        tmp[t] += x;
        __syncthreads();
    }
    if (t < NBKT) {
        int o = tmp[t] - v;
        boffs[t] = o;
        bcur[t] = o;
    }
}

// radix partition: part[] gets src | (dlocal<<18), grouped by bucket
__global__ __launch_bounds__(256) void k_bscat(const int* __restrict__ ei,
                                               int* __restrict__ bcur,
                                               uint32* __restrict__ part) {
    __shared__ int hist[NBKT];
    int tid = threadIdx.x;
    for (int i = tid; i < NBKT; i += 256) hist[i] = 0;
    __syncthreads();

    uint32 w[8];
    int bk[8], r[8];
    #pragma unroll 8
    for (int k = 0; k < 8; ++k) {
        int e = blockIdx.x * 2048 + k * 256 + tid;
        int s = ei[e];
        int d = ei[N_EDGES + e];
        int b = d >> 9;
        w[k] = (uint32)s | ((uint32)(d & 511) << 18);
        bk[k] = b;
        r[k] = atomicAdd(&hist[b], 1);
    }
    __syncthreads();
    for (int i = tid; i < NBKT; i += 256) {
        int c = hist[i];
        hist[i] = c ? atomicAdd(&bcur[i], c) : 0;
    }
    __syncthreads();
    #pragma unroll 8
    for (int k = 0; k < 8; ++k)
        part[hist[bk[k]] + r[k]] = w[k];
}

// per-bucket counting sort -> CSR ; also emits cnt/offs/dinv
__global__ __launch_bounds__(512) void k_sortb(
    const uint32* __restrict__ part, const int* __restrict__ boffs,
    const int* __restrict__ bcnt, int* __restrict__ csr,
    int* __restrict__ cnt, int* __restrict__ offs, float* __restrict__ dinv) {
    __shared__ int h[512];
    __shared__ int cur[512];
    int b = blockIdx.x, t = threadIdx.x;
    h[t] = 0;
    __syncthreads();
    int base = boffs[b], n = bcnt[b];
    for (int i = t; i < n; i += 512)
        atomicAdd(&h[part[base + i] >> 18], 1);
    __syncthreads();
    int v = h[t];
    int node = b * 512 + t;
    cnt[node] = v;
    dinv[node] = rsqrtf((float)(v + 1));        // +1 self loop
    __syncthreads();
    for (int off = 1; off < 512; off <<= 1) {
        int x = 0;
        if (t >= off) x = h[t - off];
        __syncthreads();
        h[t] += x;
        __syncthreads();
    }
    int excl = h[t] - v;
    offs[node] = base + excl;
    cur[t] = excl;
    __syncthreads();
    for (int i = t; i < n; i += 512) {
        uint32 ew = part[base + i];
        int dl = ew >> 18;
        int pos = atomicAdd(&cur[dl], 1);
        csr[base + pos] = (int)(ew & 0x3FFFF);
    }
}

// ssb[i][c] = bf16(dinv[i] * state[i][c]), packed 2 channels per uint
__global__ void k_ssb(const float* __restrict__ state, const float* __restrict__ dinv,
                      uint32* __restrict__ ssb32) {
    int idx = blockIdx.x * 256 + threadIdx.x;
    int row = idx >> 5;
    float d = dinv[row];
    float2 v = reinterpret_cast<const float2*>(state)[idx];
    ssb32[idx] = pack2bf(v.x * d, v.y * d);
}

// ---------------- GCN pull-gather (bf16) + 64x64 GEMM + relu + residual ----------------
__global__ __launch_bounds__(256) void k_gcn(
    const uint32* __restrict__ ssb32, const float* __restrict__ state,
    const int* __restrict__ csr, const int* __restrict__ offs,
    const int* __restrict__ cnt, const float* __restrict__ dinv,
    const float* __restrict__ Wg, const float* __restrict__ bg,
    ushort* __restrict__ xb16) {
    __shared__ float Wl[64 * 64];
    __shared__ float av[4][64];
    int tid = threadIdx.x;
    for (int i = tid; i < 1024; i += 256)
        reinterpret_cast<float4*>(Wl)[i] = reinterpret_cast<const float4*>(Wg)[i];

    int wave = tid >> 6, lane = tid & 63;
    int row = blockIdx.x * 4 + wave;
    int c2 = lane >> 1, odd = lane & 1;

    float di = dinv[row];
    float st = state[(size_t)row * 64 + lane];
    float a0 = 0.f, a1 = 0.f, a2 = 0.f, a3 = 0.f;
    int s0 = offs[row], c = cnt[row];
    int e = 0;
    for (; e + 4 <= c; e += 4) {
        int sa = csr[s0 + e + 0];
        int sb = csr[s0 + e + 1];
        int sc = csr[s0 + e + 2];
        int sd = csr[s0 + e + 3];
        uint32 va = ssb32[(size_t)sa * 32 + c2];
        uint32 vb = ssb32[(size_t)sb * 32 + c2];
        uint32 vc = ssb32[(size_t)sc * 32 + c2];
        uint32 vd = ssb32[(size_t)sd * 32 + c2];
        a0 += bfext(va, odd);
        a1 += bfext(vb, odd);
        a2 += bfext(vc, odd);
        a3 += bfext(vd, odd);
    }
    for (; e < c; ++e) {
        int s = csr[s0 + e];
        a0 += bfext(ssb32[(size_t)s * 32 + c2], odd);
    }
    float a = ((a0 + a1) + (a2 + a3)) * di + di * di * st;

    __syncthreads();
    av[wave][lane] = a;
    __syncthreads();

    float r = bg[lane];
    #pragma unroll
    for (int c4 = 0; c4 < 64; c4 += 4) {
        float4 a4 = *reinterpret_cast<const float4*>(&av[wave][c4]);
        r += a4.x * Wl[(c4 + 0) * 64 + lane];
        r += a4.y * Wl[(c4 + 1) * 64 + lane];
        r += a4.z * Wl[(c4 + 2) * 64 + lane];
        r += a4.w * Wl[(c4 + 3) * 64 + lane];
    }
    xb16[(size_t)row * 64 + lane] = f2bf(fmaxf(r, 0.f) + st);
}

// ---------------- pack kernels ----------------

__global__ __launch_bounds__(256) void k_packA(
    const ushort* __restrict__ xb16, const float* __restrict__ action,
    ushort* __restrict__ Ap, int grow0) {
    int tid = threadIdx.x;
    int w = tid >> 6, lane = tid & 63;
    int lr = blockIdx.x * 4 + w;
    int gr = grow0 + lr;
    int b = gr / 100, r = gr % 100;
    const float* ab = action + (size_t)b * 10000 + (size_t)r * 100;
    ushort v0 = xb16[(size_t)gr * 64 + lane];
    float v1 = ab[lane];
    float v2 = (lane < 36) ? ab[64 + lane] : 0.f;
    ushort* row = Ap + (size_t)lr * KPAD;
    row[lane] = v0;
    row[64 + lane] = f2bf(v1);
    row[128 + lane] = f2bf(v2);
}

__global__ void k_packW(const float* __restrict__ W1, const float* __restrict__ W2,
                        ushort* __restrict__ W1t, ushort* __restrict__ W2t) {
    int t = blockIdx.x * 256 + threadIdx.x;
    if (t < 256 * KPAD) {
        int j = t / KPAD, k = t % KPAD;
        W1t[t] = (k < NC + NR) ? f2bf(W1[(size_t)k * NH + j]) : (ushort)0;
    } else {
        int t2 = t - 256 * KPAD;
        if (t2 < 256 * 256) {
            int j = t2 / 256, k = t2 % 256;
            W2t[t2] = f2bf(W2[(size_t)k * NH + j]);
        }
    }
}

// ---------------- fused MLP: 64 rows x 256 hidden per block, h1 in LDS ----------------
// 4 waves; wave w owns cols w*64..w*64+63 of both layers; per-wave 64x64 tile.
__global__ __launch_bounds__(256, 3) void k_mlpf(
    const ushort* __restrict__ Ap, const ushort* __restrict__ W1t,
    const ushort* __restrict__ W2t, const float* __restrict__ b1,
    const float* __restrict__ b2, const float* __restrict__ W3,
    float* __restrict__ out, int grow0) {
    __shared__ __align__(16) ushort As[64 * 32];      // 4 KB  (epilogue: red[64][4])
    __shared__ __align__(16) ushort Bs[256 * 32];     // 16 KB
    __shared__ __align__(16) ushort H1s[64 * H1P];    // 33792 B -> 53 KB total, 3 blk/CU
    int tid = threadIdx.x;
    int w = tid >> 6, lane = tid & 63;
    int m0 = blockIdx.x * 64;                         // chunk-local row base
    int l15 = lane & 15, l4 = lane >> 4;
    int arow = tid >> 2, aseg = tid & 3;

    float b1v[4], b2v[4], w3v[4];
    #pragma unroll
    for (int nt = 0; nt < 4; ++nt) {
        int col = w * 64 + nt * 16 + l15;
        b1v[nt] = b1[col];
        b2v[nt] = b2[col];
        w3v[nt] = W3[col];
    }

    f32x4 acc[4][4] = {};

    // ---- phase 1: h1 = relu(A @ W1^T + b1), K=192 ----
    for (int kt = 0; kt < 6; ++kt) {
        int k0 = kt * 32;
        gload16(Ap + (size_t)(m0 + arow) * KPAD + k0 + aseg * 8, (char*)As + tid * 16);
        #pragma unroll
        for (int i = 0; i < 4; ++i)
            gload16(W1t + (size_t)(i * 64 + arow) * KPAD + k0 + aseg * 8,
                    (char*)Bs + i * 4096 + tid * 16);
        __syncthreads();
        short8 af[4], bf[4];
        #pragma unroll
        for (int mt = 0; mt < 4; ++mt)
            af[mt] = *(const short8*)((const char*)As + (mt * 16 + l15) * 64 + l4 * 16);
        #pragma unroll
        for (int nt = 0; nt < 4; ++nt)
            bf[nt] = *(const short8*)((const char*)Bs + (w * 64 + nt * 16 + l15) * 64 + l4 * 16);
        #pragma unroll
        for (int mt = 0; mt < 4; ++mt)
            #pragma unroll
            for (int nt = 0; nt < 4; ++nt)
                acc[mt][nt] = __builtin_amdgcn_mfma_f32_16x16x32_bf16(
                    af[mt], bf[nt], acc[mt][nt], 0, 0, 0);
        __syncthreads();
    }

    // h1 tile -> LDS (bf16, relu+bias), then reset acc
    #pragma unroll
    for (int mt = 0; mt < 4; ++mt)
        #pragma unroll
        for (int nt = 0; nt < 4; ++nt) {
            int col = w * 64 + nt * 16 + l15;
            #pragma unroll
            for (int r = 0; r < 4; ++r) {
                int row = mt * 16 + l4 * 4 + r;
                H1s[row * H1P + col] = f2bf(fmaxf(acc[mt][nt][r] + b1v[nt], 0.f));
            }
        }
    #pragma unroll
    for (int mt = 0; mt < 4; ++mt)
        #pragma unroll
        for (int nt = 0; nt < 4; ++nt)
            acc[mt][nt] = (f32x4){0.f, 0.f, 0.f, 0.f};
    __syncthreads();

    // ---- phase 2: h2 = relu(H1 @ W2^T + b2), K=256; A from LDS ----
    for (int kt = 0; kt < 8; ++kt) {
        int k0 = kt * 32;
        #pragma unroll
        for (int i = 0; i < 4; ++i)
            gload16(W2t + (size_t)(i * 64 + arow) * 256 + k0 + aseg * 8,
                    (char*)Bs + i * 4096 + tid * 16);
        __syncthreads();
        short8 af[4], bf[4];
        #pragma unroll
        for (int mt = 0; mt < 4; ++mt)
            af[mt] = *(const short8*)((const char*)H1s +
                     ((size_t)(mt * 16 + l15) * H1P + k0 + l4 * 8) * 2);
        #pragma unroll
        for (int nt = 0; nt < 4; ++nt)
            bf[nt] = *(const short8*)((const char*)Bs + (w * 64 + nt * 16 + l15) * 64 + l4 * 16);
        #pragma unroll
        for (int mt = 0; mt < 4; ++mt)
            #pragma unroll
            for (int nt = 0; nt < 4; ++nt)
                acc[mt][nt] = __builtin_amdgcn_mfma_f32_16x16x32_bf16(
                    af[mt], bf[nt], acc[mt][nt], 0, 0, 0);
        __syncthreads();
    }

    // ---- epilogue: relu + b2, xW3, row-sum, segmented per-graph reduce ----
    float* red = (float*)As;                  // [64 rows][4 waves]
    #pragma unroll
    for (int mt = 0; mt < 4; ++mt)
        #pragma unroll
        for (int r = 0; r < 4; ++r) {
            float v = 0.f;
            #pragma unroll
            for (int nt = 0; nt < 4; ++nt)
                v += fmaxf(acc[mt][nt][r] + b2v[nt], 0.f) * w3v[nt];
            v += __shfl_xor(v, 1);
            v += __shfl_xor(v, 2);
            v += __shfl_xor(v, 4);
            v += __shfl_xor(v, 8);
            if (l15 == 0) red[(mt * 16 + l4 * 4 + r) * 4 + w] = v;
        }
    __syncthreads();
    if (tid < 64) {
        float s = red[tid * 4 + 0] + red[tid * 4 + 1] + red[tid * 4 + 2] + red[tid * 4 + 3];
        int gbase = grow0 + m0;
        int g0 = gbase / 100;
        int r0 = gbase - g0 * 100;
        int split = 100 - r0; if (split > 64) split = 64;
        float v0 = (tid < split) ? s : 0.f;
        float vs = s;
        #pragma unroll
        for (int d = 1; d < 64; d <<= 1) {
            v0 += __shfl_xor(v0, d);
            vs += __shfl_xor(vs, d);
        }
        if (tid == 0) {
            atomicAdd(&out[g0], v0);
            if (split < 64) atomicAdd(&out[g0 + 1], vs - v0);
        }
    }
}

__global__ void k_init_out(float* __restrict__ out, const float* __restrict__ b3) {
    int i = blockIdx.x * 256 + threadIdx.x;
    out[i] = b3[0];
}

// ---------------- launch ----------------

extern "C" void kernel_launch(void* const* d_in, const int* in_sizes, int n_in,
                              void* d_out, int out_size, void* d_ws, size_t ws_size,
                              hipStream_t stream) {
    const float* state  = (const float*)d_in[0];
    const int*   ei     = (const int*)d_in[1];
    const float* action = (const float*)d_in[2];
    const float* Wg     = (const float*)d_in[3];
    const float* bg     = (const float*)d_in[4];
    const float* W1     = (const float*)d_in[5];
    const float* b1     = (const float*)d_in[6];
    const float* W2     = (const float*)d_in[7];
    const float* b2     = (const float*)d_in[8];
    const float* W3     = (const float*)d_in[9];
    const float* b3     = (const float*)d_in[10];
    float* out = (float*)d_out;

    char* ws = (char*)d_ws;
    // Overlays (live ranges):
    //   [0, 39.3MB)   Ap chunk (packA..mlpf) ; earlier: part [0,13.1) (bscat..sortb),
    //                 ssb32 [13.1,39.3) (ssb..gcn) — both dead before first packA
    //   [39.3, 65.5)  xb16 (gcn..packA last)
    //   [65.5, 78.6)  csr (sortb..gcn)
    ushort* Ap    = (ushort*)(ws + 0);                 // 39,321,600
    uint32* part  = (uint32*)(ws + 0);                 // 13,107,200
    uint32* ssb32 = (uint32*)(ws + 13107200);          // 26,214,400
    ushort* xb16  = (ushort*)(ws + 39321600);          // 26,214,400
    int*   csr    = (int*)  (ws + 65536000);           // 13,107,200
    int*   cnt    = (int*)  (ws + 78643200);           //    819,200
    int*   offs   = (int*)  (ws + 79462400);           //    819,200
    float* dinv   = (float*)(ws + 80281600);           //    819,200
    int*   bcnt   = (int*)  (ws + 81100800);           //      1,600
    int*   boffs  = (int*)  (ws + 81102400);           //      1,600
    int*   bcur   = (int*)  (ws + 81104000);           //      1,600
    ushort* W1t   = (ushort*)(ws + 81105600);          //     98,304
    ushort* W2t   = (ushort*)(ws + 81203904);          //    131,072 -> end 81,334,976

    hipMemsetAsync(bcnt, 0, NBKT * sizeof(int), stream);
    k_init_out<<<NB / 256, 256, 0, stream>>>(out, b3);

    k_bhist<<<N_EDGES / 2048, 256, 0, stream>>>(ei, bcnt);
    k_bscan<<<1, 512, 0, stream>>>(bcnt, boffs, bcur);
    k_bscat<<<N_EDGES / 2048, 256, 0, stream>>>(ei, bcur, part);
    k_sortb<<<NBKT, 512, 0, stream>>>(part, boffs, bcnt, csr, cnt, offs, dinv);
    k_ssb<<<(N_NODES * 32) / 256, 256, 0, stream>>>(state, dinv, ssb32);
    k_gcn<<<N_NODES / 4, 256, 0, stream>>>(ssb32, state, csr, offs, cnt, dinv, Wg, bg, xb16);
    k_packW<<<(256 * KPAD + 256 * 256 + 255) / 256, 256, 0, stream>>>(W1, W2, W1t, W2t);

    for (int c = 0; c < 2; ++c) {
        int grow0 = c * MCHUNK;
        k_packA<<<MCHUNK / 4, 256, 0, stream>>>(xb16, action, Ap, grow0);
        k_mlpf<<<MCHUNK / 64, 256, 0, stream>>>(Ap, W1t, W2t, b1, b2, W3, out, grow0);
    }
}

// Round 6
// 379.037 us; speedup vs baseline: 7.1775x; 1.2388x over previous
//
#include <hip/hip_runtime.h>
#include <hip/hip_bf16.h>
#include <cstdint>
#include <cstddef>

#define N_NODES 204800
#define N_EDGES 3276800
#define NB 2048
#define NR 100
#define NC 64
#define NH 256
#define KPAD 192          // 64 + 100 padded to 192 (6 x K32 steps)
#define MCHUNK 102400     // 204800 / 2, divisible by 64 and by 100
#define NBKT 400          // buckets of 512 dst nodes
#define H1P 264           // h1 LDS pitch (bf16)

typedef __attribute__((ext_vector_type(8))) short short8;
typedef __attribute__((ext_vector_type(4))) float f32x4;
typedef unsigned int uint32;

__device__ __forceinline__ void gload16(const void* g, void* l) {
    __builtin_amdgcn_global_load_lds(
        (const __attribute__((address_space(1))) uint32_t*)(g),
        (__attribute__((address_space(3))) uint32_t*)(l), 16, 0, 0);
}

__device__ __forceinline__ ushort f2bf(float v) {
    __hip_bfloat16 h = __float2bfloat16(v);
    return *reinterpret_cast<ushort*>(&h);
}

__device__ __forceinline__ uint32 pack2bf(float a, float b) {
    return (uint32)f2bf(a) | ((uint32)f2bf(b) << 16);
}

__device__ __forceinline__ float bflo(uint32 v) { return __uint_as_float(v << 16); }
__device__ __forceinline__ float bfhi(uint32 v) { return __uint_as_float(v & 0xFFFF0000u); }

// ---------------- bucket histogram ----------------

__global__ __launch_bounds__(256) void k_bhist(const int* __restrict__ ei,
                                               int* __restrict__ bcnt) {
    __shared__ int h[NBKT];
    int t = threadIdx.x;
    for (int i = t; i < NBKT; i += 256) h[i] = 0;
    __syncthreads();
    #pragma unroll 8
    for (int k = 0; k < 8; ++k) {
        int e = blockIdx.x * 2048 + k * 256 + t;
        atomicAdd(&h[ei[N_EDGES + e] >> 9], 1);
    }
    __syncthreads();
    for (int i = t; i < NBKT; i += 256)
        if (h[i]) atomicAdd(&bcnt[i], h[i]);
}

__global__ void k_bscan(const int* __restrict__ bcnt, int* __restrict__ boffs,
                        int* __restrict__ bcur) {
    __shared__ int tmp[512];
    int t = threadIdx.x;
    int v = (t < NBKT) ? bcnt[t] : 0;
    tmp[t] = v;
    __syncthreads();
    for (int off = 1; off < 512; off <<= 1) {
        int x = 0;
        if (t >= off) x = tmp[t - off];
        __syncthreads();
        tmp[t] += x;
        __syncthreads();
    }
    if (t < NBKT) {
        int o = tmp[t] - v;
        boffs[t] = o;
        bcur[t] = o;
    }
}

// radix partition: part[] gets src | (dlocal<<18), grouped by bucket
__global__ __launch_bounds__(256) void k_bscat(const int* __restrict__ ei,
                                               int* __restrict__ bcur,
                                               uint32* __restrict__ part) {
    __shared__ int hist[NBKT];
    int tid = threadIdx.x;
    for (int i = tid; i < NBKT; i += 256) hist[i] = 0;
    __syncthreads();

    uint32 w[8];
    int bk[8], r[8];
    #pragma unroll 8
    for (int k = 0; k < 8; ++k) {
        int e = blockIdx.x * 2048 + k * 256 + tid;
        int s = ei[e];
        int d = ei[N_EDGES + e];
        int b = d >> 9;
        w[k] = (uint32)s | ((uint32)(d & 511) << 18);
        bk[k] = b;
        r[k] = atomicAdd(&hist[b], 1);
    }
    __syncthreads();
    for (int i = tid; i < NBKT; i += 256) {
        int c = hist[i];
        hist[i] = c ? atomicAdd(&bcur[i], c) : 0;
    }
    __syncthreads();
    #pragma unroll 8
    for (int k = 0; k < 8; ++k)
        part[hist[bk[k]] + r[k]] = w[k];
}

// per-bucket counting sort -> CSR ; also emits cnt/offs/dinv
__global__ __launch_bounds__(512) void k_sortb(
    const uint32* __restrict__ part, const int* __restrict__ boffs,
    const int* __restrict__ bcnt, int* __restrict__ csr,
    int* __restrict__ cnt, int* __restrict__ offs, float* __restrict__ dinv) {
    __shared__ int h[512];
    __shared__ int cur[512];
    int b = blockIdx.x, t = threadIdx.x;
    h[t] = 0;
    __syncthreads();
    int base = boffs[b], n = bcnt[b];
    for (int i = t; i < n; i += 512)
        atomicAdd(&h[part[base + i] >> 18], 1);
    __syncthreads();
    int v = h[t];
    int node = b * 512 + t;
    cnt[node] = v;
    dinv[node] = rsqrtf((float)(v + 1));        // +1 self loop
    __syncthreads();
    for (int off = 1; off < 512; off <<= 1) {
        int x = 0;
        if (t >= off) x = h[t - off];
        __syncthreads();
        h[t] += x;
        __syncthreads();
    }
    int excl = h[t] - v;
    offs[node] = base + excl;
    cur[t] = excl;
    __syncthreads();
    for (int i = t; i < n; i += 512) {
        uint32 ew = part[base + i];
        int dl = ew >> 18;
        int pos = atomicAdd(&cur[dl], 1);
        csr[base + pos] = (int)(ew & 0x3FFFF);
    }
}

// ssb[i][c] = bf16(dinv[i] * state[i][c]), packed 2 channels per uint
__global__ void k_ssb(const float* __restrict__ state, const float* __restrict__ dinv,
                      uint32* __restrict__ ssb32) {
    int idx = blockIdx.x * 256 + threadIdx.x;
    int row = idx >> 5;
    float d = dinv[row];
    float2 v = reinterpret_cast<const float2*>(state)[idx];
    ssb32[idx] = pack2bf(v.x * d, v.y * d);
}

// ---------------- GCN: dual-row gather + MFMA xW + relu + residual ----------------
// 32 rows/block. Gather: each wave does 4 rounds of 2 rows (half-waves), each lane
// holds 2 channels. xW: wave w computes cols w*16..w*16+15 via 4 MFMA.
__global__ __launch_bounds__(256) void k_gcn(
    const uint32* __restrict__ ssb32, const float* __restrict__ state,
    const int* __restrict__ csr, const int* __restrict__ offs,
    const int* __restrict__ cnt, const float* __restrict__ dinv,
    const ushort* __restrict__ Wgt, const float* __restrict__ bg,
    ushort* __restrict__ xb16) {
    __shared__ uint32 av[32 * 36];     // [32 rows][36 dwords] (72-short pitch, 64 used)
    __shared__ ushort wgs[64 * 72];    // Wg^T padded: [n][72]
    int tid = threadIdx.x;
    int w = tid >> 6, lane = tid & 63;
    int half = lane >> 5, l = lane & 31;
    int R0 = blockIdx.x * 32;

    // stage Wg^T (bf16, n-major) -> padded LDS
    {
        int r = tid >> 2, c0 = (tid & 3) * 16;
        short8 v0 = *(const short8*)(Wgt + r * 64 + c0);
        short8 v1 = *(const short8*)(Wgt + r * 64 + c0 + 8);
        *(short8*)(wgs + r * 72 + c0) = v0;
        *(short8*)(wgs + r * 72 + c0 + 8) = v1;
    }

    for (int rr = 0; rr < 4; ++rr) {
        int lrow = w * 8 + rr * 2 + half;
        int row = R0 + lrow;
        float di = dinv[row];
        float2 st2 = *reinterpret_cast<const float2*>(state + (size_t)row * 64 + 2 * l);
        int s0 = offs[row], c = cnt[row];
        float x0 = 0.f, y0 = 0.f, x1 = 0.f, y1 = 0.f;
        float x2 = 0.f, y2 = 0.f, x3 = 0.f, y3 = 0.f;
        int e = 0;
        for (; e + 4 <= c; e += 4) {
            int sa = csr[s0 + e + 0];
            int sb = csr[s0 + e + 1];
            int sc = csr[s0 + e + 2];
            int sd = csr[s0 + e + 3];
            uint32 va = ssb32[(size_t)sa * 32 + l];
            uint32 vb = ssb32[(size_t)sb * 32 + l];
            uint32 vc = ssb32[(size_t)sc * 32 + l];
            uint32 vd = ssb32[(size_t)sd * 32 + l];
            x0 += bflo(va); y0 += bfhi(va);
            x1 += bflo(vb); y1 += bfhi(vb);
            x2 += bflo(vc); y2 += bfhi(vc);
            x3 += bflo(vd); y3 += bfhi(vd);
        }
        for (; e < c; ++e) {
            int s = csr[s0 + e];
            uint32 v = ssb32[(size_t)s * 32 + l];
            x0 += bflo(v); y0 += bfhi(v);
        }
        float ax = ((x0 + x1) + (x2 + x3)) * di + di * di * st2.x;
        float ay = ((y0 + y1) + (y2 + y3)) * di + di * di * st2.y;
        av[lrow * 36 + l] = pack2bf(ax, ay);
    }
    __syncthreads();

    // MFMA: C = av(32x64) @ Wg(64x64); wave w owns cols w*16..+15
    int l15 = lane & 15, l4 = lane >> 4;
    const ushort* avs = (const ushort*)av;
    f32x4 acc[2] = {};
    #pragma unroll
    for (int kk = 0; kk < 2; ++kk) {
        short8 bf = *(const short8*)(wgs + (w * 16 + l15) * 72 + kk * 32 + l4 * 8);
        #pragma unroll
        for (int mt = 0; mt < 2; ++mt) {
            short8 af = *(const short8*)(avs + (mt * 16 + l15) * 72 + kk * 32 + l4 * 8);
            acc[mt] = __builtin_amdgcn_mfma_f32_16x16x32_bf16(af, bf, acc[mt], 0, 0, 0);
        }
    }
    int col = w * 16 + l15;
    float bgv = bg[col];
    #pragma unroll
    for (int mt = 0; mt < 2; ++mt)
        #pragma unroll
        for (int r = 0; r < 4; ++r) {
            int row = R0 + mt * 16 + l4 * 4 + r;
            float v = fmaxf(acc[mt][r] + bgv, 0.f) + state[(size_t)row * 64 + col];
            xb16[(size_t)row * 64 + col] = f2bf(v);
        }
}

// ---------------- pack kernels ----------------

__global__ __launch_bounds__(256) void k_packA(
    const ushort* __restrict__ xb16, const float* __restrict__ action,
    ushort* __restrict__ Ap, int grow0) {
    int tid = threadIdx.x;
    int w = tid >> 6, lane = tid & 63;
    int lr = blockIdx.x * 4 + w;
    int gr = grow0 + lr;
    int b = gr / 100, r = gr % 100;
    const float* ab = action + (size_t)b * 10000 + (size_t)r * 100;
    ushort v0 = xb16[(size_t)gr * 64 + lane];
    float v1 = ab[lane];
    float v2 = (lane < 36) ? ab[64 + lane] : 0.f;
    ushort* row = Ap + (size_t)lr * KPAD;
    row[lane] = v0;
    row[64 + lane] = f2bf(v1);
    row[128 + lane] = f2bf(v2);
}

// W1t[j][k], W2t[j][k], Wgt[n][k] = transposed bf16 weights
__global__ void k_packW(const float* __restrict__ W1, const float* __restrict__ W2,
                        const float* __restrict__ Wg, ushort* __restrict__ W1t,
                        ushort* __restrict__ W2t, ushort* __restrict__ Wgt) {
    int t = blockIdx.x * 256 + threadIdx.x;
    if (t < 256 * KPAD) {
        int j = t / KPAD, k = t % KPAD;
        W1t[t] = (k < NC + NR) ? f2bf(W1[(size_t)k * NH + j]) : (ushort)0;
    } else if (t < 256 * KPAD + 256 * 256) {
        int t2 = t - 256 * KPAD;
        int j = t2 / 256, k = t2 % 256;
        W2t[t2] = f2bf(W2[(size_t)k * NH + j]);
    } else {
        int t3 = t - 256 * KPAD - 256 * 256;
        if (t3 < 64 * 64) {
            int n = t3 >> 6, k = t3 & 63;
            Wgt[t3] = f2bf(Wg[(size_t)k * 64 + n]);
        }
    }
}

// ---------------- fused MLP: 64 rows x 256 hidden per block, h1 in LDS ----------------
__global__ __launch_bounds__(256, 3) void k_mlpf(
    const ushort* __restrict__ Ap, const ushort* __restrict__ W1t,
    const ushort* __restrict__ W2t, const float* __restrict__ b1,
    const float* __restrict__ b2, const float* __restrict__ W3,
    float* __restrict__ out, int grow0) {
    __shared__ __align__(16) ushort As[64 * 32];      // 4 KB (epilogue: red[64][4])
    __shared__ __align__(16) ushort Bs[256 * 32];     // 16 KB
    __shared__ __align__(16) ushort H1s[64 * H1P];    // 33792 B
    int tid = threadIdx.x;
    int w = tid >> 6, lane = tid & 63;
    int m0 = blockIdx.x * 64;
    int l15 = lane & 15, l4 = lane >> 4;
    int arow = tid >> 2, aseg = tid & 3;

    float b1v[4], b2v[4], w3v[4];
    #pragma unroll
    for (int nt = 0; nt < 4; ++nt) {
        int col = w * 64 + nt * 16 + l15;
        b1v[nt] = b1[col];
        b2v[nt] = b2[col];
        w3v[nt] = W3[col];
    }

    f32x4 acc[4][4] = {};

    // ---- phase 1: h1 = relu(A @ W1^T + b1), K=192 ----
    for (int kt = 0; kt < 6; ++kt) {
        int k0 = kt * 32;
        gload16(Ap + (size_t)(m0 + arow) * KPAD + k0 + aseg * 8, (char*)As + tid * 16);
        #pragma unroll
        for (int i = 0; i < 4; ++i)
            gload16(W1t + (size_t)(i * 64 + arow) * KPAD + k0 + aseg * 8,
                    (char*)Bs + i * 4096 + tid * 16);
        __syncthreads();
        short8 af[4], bf[4];
        #pragma unroll
        for (int mt = 0; mt < 4; ++mt)
            af[mt] = *(const short8*)((const char*)As + (mt * 16 + l15) * 64 + l4 * 16);
        #pragma unroll
        for (int nt = 0; nt < 4; ++nt)
            bf[nt] = *(const short8*)((const char*)Bs + (w * 64 + nt * 16 + l15) * 64 + l4 * 16);
        #pragma unroll
        for (int mt = 0; mt < 4; ++mt)
            #pragma unroll
            for (int nt = 0; nt < 4; ++nt)
                acc[mt][nt] = __builtin_amdgcn_mfma_f32_16x16x32_bf16(
                    af[mt], bf[nt], acc[mt][nt], 0, 0, 0);
        __syncthreads();
    }

    #pragma unroll
    for (int mt = 0; mt < 4; ++mt)
        #pragma unroll
        for (int nt = 0; nt < 4; ++nt) {
            int col = w * 64 + nt * 16 + l15;
            #pragma unroll
            for (int r = 0; r < 4; ++r) {
                int row = mt * 16 + l4 * 4 + r;
                H1s[row * H1P + col] = f2bf(fmaxf(acc[mt][nt][r] + b1v[nt], 0.f));
            }
        }
    #pragma unroll
    for (int mt = 0; mt < 4; ++mt)
        #pragma unroll
        for (int nt = 0; nt < 4; ++nt)
            acc[mt][nt] = (f32x4){0.f, 0.f, 0.f, 0.f};
    __syncthreads();

    // ---- phase 2: h2 = relu(H1 @ W2^T + b2), K=256 ----
    for (int kt = 0; kt < 8; ++kt) {
        int k0 = kt * 32;
        #pragma unroll
        for (int i = 0; i < 4; ++i)
            gload16(W2t + (size_t)(i * 64 + arow) * 256 + k0 + aseg * 8,
                    (char*)Bs + i * 4096 + tid * 16);
        __syncthreads();
        short8 af[4], bf[4];
        #pragma unroll
        for (int mt = 0; mt < 4; ++mt)
            af[mt] = *(const short8*)((const char*)H1s +
                     ((size_t)(mt * 16 + l15) * H1P + k0 + l4 * 8) * 2);
        #pragma unroll
        for (int nt = 0; nt < 4; ++nt)
            bf[nt] = *(const short8*)((const char*)Bs + (w * 64 + nt * 16 + l15) * 64 + l4 * 16);
        #pragma unroll
        for (int mt = 0; mt < 4; ++mt)
            #pragma unroll
            for (int nt = 0; nt < 4; ++nt)
                acc[mt][nt] = __builtin_amdgcn_mfma_f32_16x16x32_bf16(
                    af[mt], bf[nt], acc[mt][nt], 0, 0, 0);
        __syncthreads();
    }

    // ---- epilogue ----
    float* red = (float*)As;
    #pragma unroll
    for (int mt = 0; mt < 4; ++mt)
        #pragma unroll
        for (int r = 0; r < 4; ++r) {
            float v = 0.f;
            #pragma unroll
            for (int nt = 0; nt < 4; ++nt)
                v += fmaxf(acc[mt][nt][r] + b2v[nt], 0.f) * w3v[nt];
            v += __shfl_xor(v, 1);
            v += __shfl_xor(v, 2);
            v += __shfl_xor(v, 4);
            v += __shfl_xor(v, 8);
            if (l15 == 0) red[(mt * 16 + l4 * 4 + r) * 4 + w] = v;
        }
    __syncthreads();
    if (tid < 64) {
        float s = red[tid * 4 + 0] + red[tid * 4 + 1] + red[tid * 4 + 2] + red[tid * 4 + 3];
        int gbase = grow0 + m0;
        int g0 = gbase / 100;
        int r0 = gbase - g0 * 100;
        int split = 100 - r0; if (split > 64) split = 64;
        float v0 = (tid < split) ? s : 0.f;
        float vs = s;
        #pragma unroll
        for (int d = 1; d < 64; d <<= 1) {
            v0 += __shfl_xor(v0, d);
            vs += __shfl_xor(vs, d);
        }
        if (tid == 0) {
            atomicAdd(&out[g0], v0);
            if (split < 64) atomicAdd(&out[g0 + 1], vs - v0);
        }
    }
}

__global__ void k_init_out(float* __restrict__ out, const float* __restrict__ b3) {
    int i = blockIdx.x * 256 + threadIdx.x;
    out[i] = b3[0];
}

// ---------------- launch ----------------

extern "C" void kernel_launch(void* const* d_in, const int* in_sizes, int n_in,
                              void* d_out, int out_size, void* d_ws, size_t ws_size,
                              hipStream_t stream) {
    const float* state  = (const float*)d_in[0];
    const int*   ei     = (const int*)d_in[1];
    const float* action = (const float*)d_in[2];
    const float* Wg     = (const float*)d_in[3];
    const float* bg     = (const float*)d_in[4];
    const float* W1     = (const float*)d_in[5];
    const float* b1     = (const float*)d_in[6];
    const float* W2     = (const float*)d_in[7];
    const float* b2     = (const float*)d_in[8];
    const float* W3     = (const float*)d_in[9];
    const float* b3     = (const float*)d_in[10];
    float* out = (float*)d_out;

    char* ws = (char*)d_ws;
    // Overlays (live ranges):
    //   [0, 39.3MB)   Ap chunk (packA..mlpf) ; earlier: part [0,13.1) (bscat..sortb),
    //                 ssb32 [13.1,39.3) (ssb..gcn) — both dead before first packA
    //   [39.3, 65.5)  xb16 (gcn..packA last)
    //   [65.5, 78.6)  csr (sortb..gcn)
    ushort* Ap    = (ushort*)(ws + 0);                 // 39,321,600
    uint32* part  = (uint32*)(ws + 0);                 // 13,107,200
    uint32* ssb32 = (uint32*)(ws + 13107200);          // 26,214,400
    ushort* xb16  = (ushort*)(ws + 39321600);          // 26,214,400
    int*   csr    = (int*)  (ws + 65536000);           // 13,107,200
    int*   cnt    = (int*)  (ws + 78643200);           //    819,200
    int*   offs   = (int*)  (ws + 79462400);           //    819,200
    float* dinv   = (float*)(ws + 80281600);           //    819,200
    int*   bcnt   = (int*)  (ws + 81100800);           //      1,600
    int*   boffs  = (int*)  (ws + 81102400);           //      1,600
    int*   bcur   = (int*)  (ws + 81104000);           //      1,600
    ushort* W1t   = (ushort*)(ws + 81105600);          //     98,304
    ushort* W2t   = (ushort*)(ws + 81203904);          //    131,072
    ushort* Wgt   = (ushort*)(ws + 81334976);          //      8,192 -> end 81,343,168

    hipMemsetAsync(bcnt, 0, NBKT * sizeof(int), stream);
    k_init_out<<<NB / 256, 256, 0, stream>>>(out, b3);

    k_bhist<<<N_EDGES / 2048, 256, 0, stream>>>(ei, bcnt);
    k_bscan<<<1, 512, 0, stream>>>(bcnt, boffs, bcur);
    k_bscat<<<N_EDGES / 2048, 256, 0, stream>>>(ei, bcur, part);
    k_sortb<<<NBKT, 512, 0, stream>>>(part, boffs, bcnt, csr, cnt, offs, dinv);
    k_ssb<<<(N_NODES * 32) / 256, 256, 0, stream>>>(state, dinv, ssb32);
    k_packW<<<(256 * KPAD + 256 * 256 + 64 * 64 + 255) / 256, 256, 0, stream>>>(
        W1, W2, Wg, W1t, W2t, Wgt);
    k_gcn<<<N_NODES / 32, 256, 0, stream>>>(ssb32, state, csr, offs, cnt, dinv,
                                            Wgt, bg, xb16);

    for (int c = 0; c < 2; ++c) {
        int grow0 = c * MCHUNK;
        k_packA<<<MCHUNK / 4, 256, 0, stream>>>(xb16, action, Ap, grow0);
        k_mlpf<<<MCHUNK / 64, 256, 0, stream>>>(Ap, W1t, W2t, b1, b2, W3, out, grow0);
    }
}

// Round 8
// 332.125 us; speedup vs baseline: 8.1913x; 1.1412x over previous
//
#include <hip/hip_runtime.h>
#include <hip/hip_bf16.h>
#include <cstdint>
#include <cstddef>

#define N_NODES 204800
#define N_EDGES 3276800
#define NB 2048
#define NR 100
#define NC 64
#define NH 256
#define KPAD 192          // 64 + 100 padded to 192 (6 x K32 steps)
#define NBKT 400          // buckets of 512 dst nodes
#define H1P 264           // h1 LDS pitch (shorts)

typedef __attribute__((ext_vector_type(8))) short short8;
typedef __attribute__((ext_vector_type(4))) float f32x4;
typedef unsigned int uint32;

__device__ __forceinline__ void gload16(const void* g, void* l) {
    __builtin_amdgcn_global_load_lds(
        (const __attribute__((address_space(1))) uint32_t*)(g),
        (__attribute__((address_space(3))) uint32_t*)(l), 16, 0, 0);
}

__device__ __forceinline__ ushort f2bf(float v) {
    __hip_bfloat16 h = __float2bfloat16(v);
    return *reinterpret_cast<ushort*>(&h);
}

__device__ __forceinline__ uint32 pack2bf(float a, float b) {
    return (uint32)f2bf(a) | ((uint32)f2bf(b) << 16);
}

__device__ __forceinline__ float bflo(uint32 v) { return __uint_as_float(v << 16); }
__device__ __forceinline__ float bfhi(uint32 v) { return __uint_as_float(v & 0xFFFF0000u); }

// ---------------- bucket histogram ----------------

__global__ __launch_bounds__(256) void k_bhist(const int* __restrict__ ei,
                                               int* __restrict__ bcnt) {
    __shared__ int h[NBKT];
    int t = threadIdx.x;
    for (int i = t; i < NBKT; i += 256) h[i] = 0;
    __syncthreads();
    #pragma unroll 8
    for (int k = 0; k < 8; ++k) {
        int e = blockIdx.x * 2048 + k * 256 + t;
        atomicAdd(&h[ei[N_EDGES + e] >> 9], 1);
    }
    __syncthreads();
    for (int i = t; i < NBKT; i += 256)
        if (h[i]) atomicAdd(&bcnt[i], h[i]);
}

__global__ void k_bscan(const int* __restrict__ bcnt, int* __restrict__ boffs,
                        int* __restrict__ bcur) {
    __shared__ int tmp[512];
    int t = threadIdx.x;
    int v = (t < NBKT) ? bcnt[t] : 0;
    tmp[t] = v;
    __syncthreads();
    for (int off = 1; off < 512; off <<= 1) {
        int x = 0;
        if (t >= off) x = tmp[t - off];
        __syncthreads();
        tmp[t] += x;
        __syncthreads();
    }
    if (t < NBKT) {
        int o = tmp[t] - v;
        boffs[t] = o;
        bcur[t] = o;
    }
}

// radix partition: part[] gets src | (dlocal<<18), grouped by bucket
__global__ __launch_bounds__(256) void k_bscat(const int* __restrict__ ei,
                                               int* __restrict__ bcur,
                                               uint32* __restrict__ part) {
    __shared__ int hist[NBKT];
    int tid = threadIdx.x;
    for (int i = tid; i < NBKT; i += 256) hist[i] = 0;
    __syncthreads();

    uint32 w[8];
    int bk[8], r[8];
    #pragma unroll 8
    for (int k = 0; k < 8; ++k) {
        int e = blockIdx.x * 2048 + k * 256 + tid;
        int s = ei[e];
        int d = ei[N_EDGES + e];
        int b = d >> 9;
        w[k] = (uint32)s | ((uint32)(d & 511) << 18);
        bk[k] = b;
        r[k] = atomicAdd(&hist[b], 1);
    }
    __syncthreads();
    for (int i = tid; i < NBKT; i += 256) {
        int c = hist[i];
        hist[i] = c ? atomicAdd(&bcur[i], c) : 0;
    }
    __syncthreads();
    #pragma unroll 8
    for (int k = 0; k < 8; ++k)
        part[hist[bk[k]] + r[k]] = w[k];
}

// per-bucket counting sort -> CSR ; also emits cnt/offs/dinv
__global__ __launch_bounds__(512) void k_sortb(
    const uint32* __restrict__ part, const int* __restrict__ boffs,
    const int* __restrict__ bcnt, int* __restrict__ csr,
    int* __restrict__ cnt, int* __restrict__ offs, float* __restrict__ dinv) {
    __shared__ int h[512];
    __shared__ int cur[512];
    int b = blockIdx.x, t = threadIdx.x;
    h[t] = 0;
    __syncthreads();
    int base = boffs[b], n = bcnt[b];
    for (int i = t; i < n; i += 512)
        atomicAdd(&h[part[base + i] >> 18], 1);
    __syncthreads();
    int v = h[t];
    int node = b * 512 + t;
    cnt[node] = v;
    dinv[node] = rsqrtf((float)(v + 1));        // +1 self loop
    __syncthreads();
    for (int off = 1; off < 512; off <<= 1) {
        int x = 0;
        if (t >= off) x = h[t - off];
        __syncthreads();
        h[t] += x;
        __syncthreads();
    }
    int excl = h[t] - v;
    offs[node] = base + excl;
    cur[t] = excl;
    __syncthreads();
    for (int i = t; i < n; i += 512) {
        uint32 ew = part[base + i];
        int dl = ew >> 18;
        int pos = atomicAdd(&cur[dl], 1);
        csr[base + pos] = (int)(ew & 0x3FFFF);
    }
}

// ssb[i][c] = bf16(dinv[i] * state[i][c]), packed 2 channels per uint
__global__ void k_ssb(const float* __restrict__ state, const float* __restrict__ dinv,
                      uint32* __restrict__ ssb32) {
    int idx = blockIdx.x * 256 + threadIdx.x;
    int row = idx >> 5;
    float d = dinv[row];
    float2 v = reinterpret_cast<const float2*>(state)[idx];
    ssb32[idx] = pack2bf(v.x * d, v.y * d);
}

// ---------------- GCN: dual-row gather (unroll 8) + MFMA xW + relu + residual ----------------
__global__ __launch_bounds__(256) void k_gcn(
    const uint32* __restrict__ ssb32, const float* __restrict__ state,
    const int* __restrict__ csr, const int* __restrict__ offs,
    const int* __restrict__ cnt, const float* __restrict__ dinv,
    const ushort* __restrict__ Wgt, const float* __restrict__ bg,
    ushort* __restrict__ xb16) {
    __shared__ uint32 av[32 * 36];     // [32 rows][36 dwords] (72-short pitch)
    __shared__ ushort wgs[64 * 72];    // Wg^T padded: [n][72]
    int tid = threadIdx.x;
    int w = tid >> 6, lane = tid & 63;
    int half = lane >> 5, l = lane & 31;
    int R0 = blockIdx.x * 32;

    // stage Wg^T (bf16, n-major) -> padded LDS
    {
        int r = tid >> 2, c0 = (tid & 3) * 16;
        short8 v0 = *(const short8*)(Wgt + r * 64 + c0);
        short8 v1 = *(const short8*)(Wgt + r * 64 + c0 + 8);
        *(short8*)(wgs + r * 72 + c0) = v0;
        *(short8*)(wgs + r * 72 + c0 + 8) = v1;
    }

    for (int rr = 0; rr < 4; ++rr) {
        int lrow = w * 8 + rr * 2 + half;
        int row = R0 + lrow;
        float di = dinv[row];
        float2 st2 = *reinterpret_cast<const float2*>(state + (size_t)row * 64 + 2 * l);
        int s0 = offs[row], c = cnt[row];
        float x0 = 0.f, y0 = 0.f, x1 = 0.f, y1 = 0.f;
        float x2 = 0.f, y2 = 0.f, x3 = 0.f, y3 = 0.f;
        int e = 0;
        for (; e + 8 <= c; e += 8) {
            int sa = csr[s0 + e + 0];
            int sb = csr[s0 + e + 1];
            int sc = csr[s0 + e + 2];
            int sd = csr[s0 + e + 3];
            int se = csr[s0 + e + 4];
            int sf = csr[s0 + e + 5];
            int sg = csr[s0 + e + 6];
            int sh = csr[s0 + e + 7];
            uint32 va = ssb32[(size_t)sa * 32 + l];
            uint32 vb = ssb32[(size_t)sb * 32 + l];
            uint32 vc = ssb32[(size_t)sc * 32 + l];
            uint32 vd = ssb32[(size_t)sd * 32 + l];
            uint32 ve = ssb32[(size_t)se * 32 + l];
            uint32 vf = ssb32[(size_t)sf * 32 + l];
            uint32 vg = ssb32[(size_t)sg * 32 + l];
            uint32 vh = ssb32[(size_t)sh * 32 + l];
            x0 += bflo(va); y0 += bfhi(va);
            x1 += bflo(vb); y1 += bfhi(vb);
            x2 += bflo(vc); y2 += bfhi(vc);
            x3 += bflo(vd); y3 += bfhi(vd);
            x0 += bflo(ve); y0 += bfhi(ve);
            x1 += bflo(vf); y1 += bfhi(vf);
            x2 += bflo(vg); y2 += bfhi(vg);
            x3 += bflo(vh); y3 += bfhi(vh);
        }
        for (; e + 4 <= c; e += 4) {
            int sa = csr[s0 + e + 0];
            int sb = csr[s0 + e + 1];
            int sc = csr[s0 + e + 2];
            int sd = csr[s0 + e + 3];
            uint32 va = ssb32[(size_t)sa * 32 + l];
            uint32 vb = ssb32[(size_t)sb * 32 + l];
            uint32 vc = ssb32[(size_t)sc * 32 + l];
            uint32 vd = ssb32[(size_t)sd * 32 + l];
            x0 += bflo(va); y0 += bfhi(va);
            x1 += bflo(vb); y1 += bfhi(vb);
            x2 += bflo(vc); y2 += bfhi(vc);
            x3 += bflo(vd); y3 += bfhi(vd);
        }
        for (; e < c; ++e) {
            int s = csr[s0 + e];
            uint32 v = ssb32[(size_t)s * 32 + l];
            x0 += bflo(v); y0 += bfhi(v);
        }
        float ax = ((x0 + x1) + (x2 + x3)) * di + di * di * st2.x;
        float ay = ((y0 + y1) + (y2 + y3)) * di + di * di * st2.y;
        av[lrow * 36 + l] = pack2bf(ax, ay);
    }
    __syncthreads();

    // MFMA: C = av(32x64) @ Wg(64x64); wave w owns cols w*16..+15
    int l15 = lane & 15, l4 = lane >> 4;
    const ushort* avs = (const ushort*)av;
    f32x4 acc[2] = {};
    #pragma unroll
    for (int kk = 0; kk < 2; ++kk) {
        short8 bf = *(const short8*)(wgs + (w * 16 + l15) * 72 + kk * 32 + l4 * 8);
        #pragma unroll
        for (int mt = 0; mt < 2; ++mt) {
            short8 af = *(const short8*)(avs + (mt * 16 + l15) * 72 + kk * 32 + l4 * 8);
            acc[mt] = __builtin_amdgcn_mfma_f32_16x16x32_bf16(af, bf, acc[mt], 0, 0, 0);
        }
    }
    int col = w * 16 + l15;
    float bgv = bg[col];
    #pragma unroll
    for (int mt = 0; mt < 2; ++mt)
        #pragma unroll
        for (int r = 0; r < 4; ++r) {
            int row = R0 + mt * 16 + l4 * 4 + r;
            float v = fmaxf(acc[mt][r] + bgv, 0.f) + state[(size_t)row * 64 + col];
            xb16[(size_t)row * 64 + col] = f2bf(v);
        }
}

// W1t[j][k], W2t[j][k], Wgt[n][k] = transposed bf16 weights
__global__ void k_packW(const float* __restrict__ W1, const float* __restrict__ W2,
                        const float* __restrict__ Wg, ushort* __restrict__ W1t,
                        ushort* __restrict__ W2t, ushort* __restrict__ Wgt) {
    int t = blockIdx.x * 256 + threadIdx.x;
    if (t < 256 * KPAD) {
        int j = t / KPAD, k = t % KPAD;
        W1t[t] = (k < NC + NR) ? f2bf(W1[(size_t)k * NH + j]) : (ushort)0;
    } else if (t < 256 * KPAD + 256 * 256) {
        int t2 = t - 256 * KPAD;
        int j = t2 / 256, k = t2 % 256;
        W2t[t2] = f2bf(W2[(size_t)k * NH + j]);
    } else {
        int t3 = t - 256 * KPAD - 256 * 256;
        if (t3 < 64 * 64) {
            int n = t3 >> 6, k = t3 & 63;
            Wgt[t3] = f2bf(Wg[(size_t)k * 64 + n]);
        }
    }
}

// ---------------- fused MLP: 64 rows x 256 hidden per block (round-5 body; ----------------
// A-tile staged per kt: kt<2 from xb16 via global_load_lds, kt>=2 from action w/ cvt+zero)
__global__ __launch_bounds__(256, 3) void k_mlpf(
    const ushort* __restrict__ xb16, const float* __restrict__ action,
    const ushort* __restrict__ W1t, const ushort* __restrict__ W2t,
    const float* __restrict__ b1, const float* __restrict__ b2,
    const float* __restrict__ W3, float* __restrict__ out) {
    __shared__ __align__(16) ushort As[64 * 32];      // 4 KB (epilogue: red[64][4])
    __shared__ __align__(16) ushort Bs[256 * 32];     // 16 KB
    __shared__ __align__(16) ushort H1s[64 * H1P];    // 33792 B -> 54272 B total
    int tid = threadIdx.x;
    int w = tid >> 6, lane = tid & 63;
    int m0 = blockIdx.x * 64;
    int l15 = lane & 15, l4 = lane >> 4;
    int arow = tid >> 2, aseg = tid & 3;

    // per-thread action row pointer (this thread always stages row m0+arow)
    int gr = m0 + arow;
    int gb = gr / 100, grr = gr - gb * 100;
    const float* abp = action + (size_t)gb * 10000 + (size_t)grr * 100;

    float b1v[4], b2v[4], w3v[4];
    #pragma unroll
    for (int nt = 0; nt < 4; ++nt) {
        int col = w * 64 + nt * 16 + l15;
        b1v[nt] = b1[col];
        b2v[nt] = b2[col];
        w3v[nt] = W3[col];
    }

    f32x4 acc[4][4] = {};

    // ---- phase 1: h1 = relu(concat(x,action) @ W1^T + b1), K=192 ----
    for (int kt = 0; kt < 6; ++kt) {
        int k0 = kt * 32;
        if (kt < 2) {
            gload16(xb16 + (size_t)(m0 + arow) * 64 + k0 + aseg * 8,
                    (char*)As + tid * 16);
        } else {
            int col0 = (k0 - 64) + aseg * 8;
            ushort tmp[8];
            #pragma unroll
            for (int u = 0; u < 8; ++u) {
                int cc = col0 + u;
                tmp[u] = (cc < NR) ? f2bf(abp[cc]) : (ushort)0;
            }
            *(short8*)((char*)As + tid * 16) = *(const short8*)tmp;
        }
        #pragma unroll
        for (int i = 0; i < 4; ++i)
            gload16(W1t + (size_t)(i * 64 + arow) * KPAD + k0 + aseg * 8,
                    (char*)Bs + i * 4096 + tid * 16);
        __syncthreads();
        short8 af[4], bf[4];
        #pragma unroll
        for (int mt = 0; mt < 4; ++mt)
            af[mt] = *(const short8*)((const char*)As + (mt * 16 + l15) * 64 + l4 * 16);
        #pragma unroll
        for (int nt = 0; nt < 4; ++nt)
            bf[nt] = *(const short8*)((const char*)Bs + (w * 64 + nt * 16 + l15) * 64 + l4 * 16);
        #pragma unroll
        for (int mt = 0; mt < 4; ++mt)
            #pragma unroll
            for (int nt = 0; nt < 4; ++nt)
                acc[mt][nt] = __builtin_amdgcn_mfma_f32_16x16x32_bf16(
                    af[mt], bf[nt], acc[mt][nt], 0, 0, 0);
        __syncthreads();
    }

    // h1 tile -> H1s (bf16, relu+bias), then reset acc
    #pragma unroll
    for (int mt = 0; mt < 4; ++mt)
        #pragma unroll
        for (int nt = 0; nt < 4; ++nt) {
            int col = w * 64 + nt * 16 + l15;
            #pragma unroll
            for (int r = 0; r < 4; ++r) {
                int row = mt * 16 + l4 * 4 + r;
                H1s[row * H1P + col] = f2bf(fmaxf(acc[mt][nt][r] + b1v[nt], 0.f));
            }
        }
    #pragma unroll
    for (int mt = 0; mt < 4; ++mt)
        #pragma unroll
        for (int nt = 0; nt < 4; ++nt)
            acc[mt][nt] = (f32x4){0.f, 0.f, 0.f, 0.f};
    __syncthreads();

    // ---- phase 2: h2 = relu(H1 @ W2^T + b2), K=256 ----
    for (int kt = 0; kt < 8; ++kt) {
        int k0 = kt * 32;
        #pragma unroll
        for (int i = 0; i < 4; ++i)
            gload16(W2t + (size_t)(i * 64 + arow) * 256 + k0 + aseg * 8,
                    (char*)Bs + i * 4096 + tid * 16);
        __syncthreads();
        short8 af[4], bf[4];
        #pragma unroll
        for (int mt = 0; mt < 4; ++mt)
            af[mt] = *(const short8*)((const char*)H1s +
                     ((size_t)(mt * 16 + l15) * H1P + k0 + l4 * 8) * 2);
        #pragma unroll
        for (int nt = 0; nt < 4; ++nt)
            bf[nt] = *(const short8*)((const char*)Bs + (w * 64 + nt * 16 + l15) * 64 + l4 * 16);
        #pragma unroll
        for (int mt = 0; mt < 4; ++mt)
            #pragma unroll
            for (int nt = 0; nt < 4; ++nt)
                acc[mt][nt] = __builtin_amdgcn_mfma_f32_16x16x32_bf16(
                    af[mt], bf[nt], acc[mt][nt], 0, 0, 0);
        __syncthreads();
    }

    // ---- epilogue: relu + b2, xW3, row-sum, per-graph segmented reduce ----
    float* red = (float*)As;                  // [64 rows][4 waves]
    #pragma unroll
    for (int mt = 0; mt < 4; ++mt)
        #pragma unroll
        for (int r = 0; r < 4; ++r) {
            float v = 0.f;
            #pragma unroll
            for (int nt = 0; nt < 4; ++nt)
                v += fmaxf(acc[mt][nt][r] + b2v[nt], 0.f) * w3v[nt];
            v += __shfl_xor(v, 1);
            v += __shfl_xor(v, 2);
            v += __shfl_xor(v, 4);
            v += __shfl_xor(v, 8);
            if (l15 == 0) red[(mt * 16 + l4 * 4 + r) * 4 + w] = v;
        }
    __syncthreads();
    if (tid < 64) {
        float s = red[tid * 4 + 0] + red[tid * 4 + 1] + red[tid * 4 + 2] + red[tid * 4 + 3];
        int gbase = m0;
        int g0 = gbase / 100;
        int r0 = gbase - g0 * 100;
        int split = 100 - r0; if (split > 64) split = 64;
        float v0 = (tid < split) ? s : 0.f;
        float vs = s;
        #pragma unroll
        for (int d = 1; d < 64; d <<= 1) {
            v0 += __shfl_xor(v0, d);
            vs += __shfl_xor(vs, d);
        }
        if (tid == 0) {
            atomicAdd(&out[g0], v0);
            if (split < 64) atomicAdd(&out[g0 + 1], vs - v0);
        }
    }
}

__global__ void k_init_out(float* __restrict__ out, const float* __restrict__ b3) {
    int i = blockIdx.x * 256 + threadIdx.x;
    out[i] = b3[0];
}

// ---------------- launch ----------------

extern "C" void kernel_launch(void* const* d_in, const int* in_sizes, int n_in,
                              void* d_out, int out_size, void* d_ws, size_t ws_size,
                              hipStream_t stream) {
    const float* state  = (const float*)d_in[0];
    const int*   ei     = (const int*)d_in[1];
    const float* action = (const float*)d_in[2];
    const float* Wg     = (const float*)d_in[3];
    const float* bg     = (const float*)d_in[4];
    const float* W1     = (const float*)d_in[5];
    const float* b1     = (const float*)d_in[6];
    const float* W2     = (const float*)d_in[7];
    const float* b2     = (const float*)d_in[8];
    const float* W3     = (const float*)d_in[9];
    const float* b3     = (const float*)d_in[10];
    float* out = (float*)d_out;

    char* ws = (char*)d_ws;
    // Overlays (live ranges):
    //   [0, 13.1MB)     part (bscat..sortb)
    //   [13.1, 39.3)    ssb32 (ssb..gcn)
    //   [39.3, 65.5)    xb16 (gcn..mlpf)
    //   [65.5, 78.6)    csr (sortb..gcn)
    uint32* part  = (uint32*)(ws + 0);                 // 13,107,200
    uint32* ssb32 = (uint32*)(ws + 13107200);          // 26,214,400
    ushort* xb16  = (ushort*)(ws + 39321600);          // 26,214,400
    int*   csr    = (int*)  (ws + 65536000);           // 13,107,200
    int*   cnt    = (int*)  (ws + 78643200);           //    819,200
    int*   offs   = (int*)  (ws + 79462400);           //    819,200
    float* dinv   = (float*)(ws + 80281600);           //    819,200
    int*   bcnt   = (int*)  (ws + 81100800);           //      1,600
    int*   boffs  = (int*)  (ws + 81102400);           //      1,600
    int*   bcur   = (int*)  (ws + 81104000);           //      1,600
    ushort* W1t   = (ushort*)(ws + 81105600);          //     98,304
    ushort* W2t   = (ushort*)(ws + 81203904);          //    131,072
    ushort* Wgt   = (ushort*)(ws + 81334976);          //      8,192 -> end 81,343,168

    hipMemsetAsync(bcnt, 0, NBKT * sizeof(int), stream);
    k_init_out<<<NB / 256, 256, 0, stream>>>(out, b3);

    k_bhist<<<N_EDGES / 2048, 256, 0, stream>>>(ei, bcnt);
    k_bscan<<<1, 512, 0, stream>>>(bcnt, boffs, bcur);
    k_bscat<<<N_EDGES / 2048, 256, 0, stream>>>(ei, bcur, part);
    k_sortb<<<NBKT, 512, 0, stream>>>(part, boffs, bcnt, csr, cnt, offs, dinv);
    k_ssb<<<(N_NODES * 32) / 256, 256, 0, stream>>>(state, dinv, ssb32);
    k_packW<<<(256 * KPAD + 256 * 256 + 64 * 64 + 255) / 256, 256, 0, stream>>>(
        W1, W2, Wg, W1t, W2t, Wgt);
    k_gcn<<<N_NODES / 32, 256, 0, stream>>>(ssb32, state, csr, offs, cnt, dinv,
                                            Wgt, bg, xb16);
    k_mlpf<<<N_NODES / 64, 256, 0, stream>>>(xb16, action, W1t, W2t, b1, b2, W3, out);
}

// Round 9
// 324.656 us; speedup vs baseline: 8.3797x; 1.0230x over previous
//
#include <hip/hip_runtime.h>
#include <hip/hip_bf16.h>
#include <cstdint>
#include <cstddef>

#define N_NODES 204800
#define N_EDGES 3276800
#define NB 2048
#define NR 100
#define NC 64
#define NH 256
#define KPAD 192          // 64 + 100 padded to 192 (6 x K32 steps)
#define NBKT 400          // buckets of 512 dst nodes
#define H1P 264           // h1 LDS pitch (shorts): 33-slot rows -> conflict-free frag reads

typedef __attribute__((ext_vector_type(8))) short short8;
typedef __attribute__((ext_vector_type(4))) float f32x4;
typedef unsigned int uint32;

__device__ __forceinline__ void gload16(const void* g, void* l) {
    __builtin_amdgcn_global_load_lds(
        (const __attribute__((address_space(1))) uint32_t*)(g),
        (__attribute__((address_space(3))) uint32_t*)(l), 16, 0, 0);
}

__device__ __forceinline__ ushort f2bf(float v) {
    __hip_bfloat16 h = __float2bfloat16(v);
    return *reinterpret_cast<ushort*>(&h);
}

__device__ __forceinline__ uint32 pack2bf(float a, float b) {
    return (uint32)f2bf(a) | ((uint32)f2bf(b) << 16);
}

__device__ __forceinline__ float bflo(uint32 v) { return __uint_as_float(v << 16); }
__device__ __forceinline__ float bfhi(uint32 v) { return __uint_as_float(v & 0xFFFF0000u); }

// ---------------- bucket histogram ----------------

__global__ __launch_bounds__(256) void k_bhist(const int* __restrict__ ei,
                                               int* __restrict__ bcnt) {
    __shared__ int h[NBKT];
    int t = threadIdx.x;
    for (int i = t; i < NBKT; i += 256) h[i] = 0;
    __syncthreads();
    #pragma unroll 8
    for (int k = 0; k < 8; ++k) {
        int e = blockIdx.x * 2048 + k * 256 + t;
        atomicAdd(&h[ei[N_EDGES + e] >> 9], 1);
    }
    __syncthreads();
    for (int i = t; i < NBKT; i += 256)
        if (h[i]) atomicAdd(&bcnt[i], h[i]);
}

__global__ void k_bscan(const int* __restrict__ bcnt, int* __restrict__ boffs,
                        int* __restrict__ bcur) {
    __shared__ int tmp[512];
    int t = threadIdx.x;
    int v = (t < NBKT) ? bcnt[t] : 0;
    tmp[t] = v;
    __syncthreads();
    for (int off = 1; off < 512; off <<= 1) {
        int x = 0;
        if (t >= off) x = tmp[t - off];
        __syncthreads();
        tmp[t] += x;
        __syncthreads();
    }
    if (t < NBKT) {
        int o = tmp[t] - v;
        boffs[t] = o;
        bcur[t] = o;
    }
}

// radix partition: part[] gets src | (dlocal<<18), grouped by bucket
__global__ __launch_bounds__(256) void k_bscat(const int* __restrict__ ei,
                                               int* __restrict__ bcur,
                                               uint32* __restrict__ part) {
    __shared__ int hist[NBKT];
    int tid = threadIdx.x;
    for (int i = tid; i < NBKT; i += 256) hist[i] = 0;
    __syncthreads();

    uint32 w[8];
    int bk[8], r[8];
    #pragma unroll 8
    for (int k = 0; k < 8; ++k) {
        int e = blockIdx.x * 2048 + k * 256 + tid;
        int s = ei[e];
        int d = ei[N_EDGES + e];
        int b = d >> 9;
        w[k] = (uint32)s | ((uint32)(d & 511) << 18);
        bk[k] = b;
        r[k] = atomicAdd(&hist[b], 1);
    }
    __syncthreads();
    for (int i = tid; i < NBKT; i += 256) {
        int c = hist[i];
        hist[i] = c ? atomicAdd(&bcur[i], c) : 0;
    }
    __syncthreads();
    #pragma unroll 8
    for (int k = 0; k < 8; ++k)
        part[hist[bk[k]] + r[k]] = w[k];
}

// per-bucket counting sort -> CSR ; also emits cnt/offs/dinv
__global__ __launch_bounds__(512) void k_sortb(
    const uint32* __restrict__ part, const int* __restrict__ boffs,
    const int* __restrict__ bcnt, int* __restrict__ csr,
    int* __restrict__ cnt, int* __restrict__ offs, float* __restrict__ dinv) {
    __shared__ int h[512];
    __shared__ int cur[512];
    int b = blockIdx.x, t = threadIdx.x;
    h[t] = 0;
    __syncthreads();
    int base = boffs[b], n = bcnt[b];
    for (int i = t; i < n; i += 512)
        atomicAdd(&h[part[base + i] >> 18], 1);
    __syncthreads();
    int v = h[t];
    int node = b * 512 + t;
    cnt[node] = v;
    dinv[node] = rsqrtf((float)(v + 1));        // +1 self loop
    __syncthreads();
    for (int off = 1; off < 512; off <<= 1) {
        int x = 0;
        if (t >= off) x = h[t - off];
        __syncthreads();
        h[t] += x;
        __syncthreads();
    }
    int excl = h[t] - v;
    offs[node] = base + excl;
    cur[t] = excl;
    __syncthreads();
    for (int i = t; i < n; i += 512) {
        uint32 ew = part[base + i];
        int dl = ew >> 18;
        int pos = atomicAdd(&cur[dl], 1);
        csr[base + pos] = (int)(ew & 0x3FFFF);
    }
}

// ssb[i][c] = bf16(dinv[i] * state[i][c]), packed 2 channels per uint
__global__ void k_ssb(const float* __restrict__ state, const float* __restrict__ dinv,
                      uint32* __restrict__ ssb32) {
    int idx = blockIdx.x * 256 + threadIdx.x;
    int row = idx >> 5;
    float d = dinv[row];
    float2 v = reinterpret_cast<const float2*>(state)[idx];
    ssb32[idx] = pack2bf(v.x * d, v.y * d);
}

// ---------------- GCN: dual-row gather (unroll 8) + MFMA xW + relu + residual ----------------
__global__ __launch_bounds__(256) void k_gcn(
    const uint32* __restrict__ ssb32, const float* __restrict__ state,
    const int* __restrict__ csr, const int* __restrict__ offs,
    const int* __restrict__ cnt, const float* __restrict__ dinv,
    const ushort* __restrict__ Wgt, const float* __restrict__ bg,
    ushort* __restrict__ xb16) {
    __shared__ uint32 av[32 * 36];     // [32 rows][36 dwords] (72-short pitch)
    __shared__ ushort wgs[64 * 72];    // Wg^T padded: [n][72]
    int tid = threadIdx.x;
    int w = tid >> 6, lane = tid & 63;
    int half = lane >> 5, l = lane & 31;
    int R0 = blockIdx.x * 32;

    // stage Wg^T (bf16, n-major) -> padded LDS
    {
        int r = tid >> 2, c0 = (tid & 3) * 16;
        short8 v0 = *(const short8*)(Wgt + r * 64 + c0);
        short8 v1 = *(const short8*)(Wgt + r * 64 + c0 + 8);
        *(short8*)(wgs + r * 72 + c0) = v0;
        *(short8*)(wgs + r * 72 + c0 + 8) = v1;
    }

    for (int rr = 0; rr < 4; ++rr) {
        int lrow = w * 8 + rr * 2 + half;
        int row = R0 + lrow;
        float di = dinv[row];
        float2 st2 = *reinterpret_cast<const float2*>(state + (size_t)row * 64 + 2 * l);
        int s0 = offs[row], c = cnt[row];
        float x0 = 0.f, y0 = 0.f, x1 = 0.f, y1 = 0.f;
        float x2 = 0.f, y2 = 0.f, x3 = 0.f, y3 = 0.f;
        int e = 0;
        for (; e + 8 <= c; e += 8) {
            int sa = csr[s0 + e + 0];
            int sb = csr[s0 + e + 1];
            int sc = csr[s0 + e + 2];
            int sd = csr[s0 + e + 3];
            int se = csr[s0 + e + 4];
            int sf = csr[s0 + e + 5];
            int sg = csr[s0 + e + 6];
            int sh = csr[s0 + e + 7];
            uint32 va = ssb32[(size_t)sa * 32 + l];
            uint32 vb = ssb32[(size_t)sb * 32 + l];
            uint32 vc = ssb32[(size_t)sc * 32 + l];
            uint32 vd = ssb32[(size_t)sd * 32 + l];
            uint32 ve = ssb32[(size_t)se * 32 + l];
            uint32 vf = ssb32[(size_t)sf * 32 + l];
            uint32 vg = ssb32[(size_t)sg * 32 + l];
            uint32 vh = ssb32[(size_t)sh * 32 + l];
            x0 += bflo(va); y0 += bfhi(va);
            x1 += bflo(vb); y1 += bfhi(vb);
            x2 += bflo(vc); y2 += bfhi(vc);
            x3 += bflo(vd); y3 += bfhi(vd);
            x0 += bflo(ve); y0 += bfhi(ve);
            x1 += bflo(vf); y1 += bfhi(vf);
            x2 += bflo(vg); y2 += bfhi(vg);
            x3 += bflo(vh); y3 += bfhi(vh);
        }
        for (; e + 4 <= c; e += 4) {
            int sa = csr[s0 + e + 0];
            int sb = csr[s0 + e + 1];
            int sc = csr[s0 + e + 2];
            int sd = csr[s0 + e + 3];
            uint32 va = ssb32[(size_t)sa * 32 + l];
            uint32 vb = ssb32[(size_t)sb * 32 + l];
            uint32 vc = ssb32[(size_t)sc * 32 + l];
            uint32 vd = ssb32[(size_t)sd * 32 + l];
            x0 += bflo(va); y0 += bfhi(va);
            x1 += bflo(vb); y1 += bfhi(vb);
            x2 += bflo(vc); y2 += bfhi(vc);
            x3 += bflo(vd); y3 += bfhi(vd);
        }
        for (; e < c; ++e) {
            int s = csr[s0 + e];
            uint32 v = ssb32[(size_t)s * 32 + l];
            x0 += bflo(v); y0 += bfhi(v);
        }
        float ax = ((x0 + x1) + (x2 + x3)) * di + di * di * st2.x;
        float ay = ((y0 + y1) + (y2 + y3)) * di + di * di * st2.y;
        av[lrow * 36 + l] = pack2bf(ax, ay);
    }
    __syncthreads();

    // MFMA: C = av(32x64) @ Wg(64x64); wave w owns cols w*16..+15
    int l15 = lane & 15, l4 = lane >> 4;
    const ushort* avs = (const ushort*)av;
    f32x4 acc[2] = {};
    #pragma unroll
    for (int kk = 0; kk < 2; ++kk) {
        short8 bf = *(const short8*)(wgs + (w * 16 + l15) * 72 + kk * 32 + l4 * 8);
        #pragma unroll
        for (int mt = 0; mt < 2; ++mt) {
            short8 af = *(const short8*)(avs + (mt * 16 + l15) * 72 + kk * 32 + l4 * 8);
            acc[mt] = __builtin_amdgcn_mfma_f32_16x16x32_bf16(af, bf, acc[mt], 0, 0, 0);
        }
    }
    int col = w * 16 + l15;
    float bgv = bg[col];
    #pragma unroll
    for (int mt = 0; mt < 2; ++mt)
        #pragma unroll
        for (int r = 0; r < 4; ++r) {
            int row = R0 + mt * 16 + l4 * 4 + r;
            float v = fmaxf(acc[mt][r] + bgv, 0.f) + state[(size_t)row * 64 + col];
            xb16[(size_t)row * 64 + col] = f2bf(v);
        }
}

// ---------------- pack weights: FRAGMENT-MAJOR for k_mlpf ----------------
// chunk id = (kt*4+i)*256 + tid, tid = wp*64+l. Chunk short u:
//   k = kt*32 + (l>>4)*8 + u ;  j (output col) = i*64 + wp*16 + (l&15)
// This makes both the gload16 stage AND the ds_read_b128 fragment reads lane-linear.
__global__ void k_packW(const float* __restrict__ W1, const float* __restrict__ W2,
                        const float* __restrict__ Wg, ushort* __restrict__ W1f,
                        ushort* __restrict__ W2f, ushort* __restrict__ Wgt) {
    int t = blockIdx.x * 256 + threadIdx.x;
    if (t < 6 * 4 * 256 * 8) {                      // W1f: 49152 shorts
        int u = t & 7, chunk = t >> 3;
        int tid = chunk & 255, ktI = chunk >> 8;
        int kt = ktI >> 2, i = ktI & 3;
        int l = tid & 63, wp = tid >> 6;
        int k = kt * 32 + (l >> 4) * 8 + u;
        int j = i * 64 + wp * 16 + (l & 15);
        W1f[t] = (k < NC + NR) ? f2bf(W1[(size_t)k * NH + j]) : (ushort)0;
    } else if (t < 49152 + 8 * 4 * 256 * 8) {       // W2f: 65536 shorts
        int t2 = t - 49152;
        int u = t2 & 7, chunk = t2 >> 3;
        int tid = chunk & 255, ktI = chunk >> 8;
        int kt = ktI >> 2, i = ktI & 3;
        int l = tid & 63, wp = tid >> 6;
        int k = kt * 32 + (l >> 4) * 8 + u;
        int j = i * 64 + wp * 16 + (l & 15);
        W2f[t2] = f2bf(W2[(size_t)k * NH + j]);
    } else {
        int t3 = t - 49152 - 65536;
        if (t3 < 64 * 64) {
            int n = t3 >> 6, k = t3 & 63;
            Wgt[t3] = f2bf(Wg[(size_t)k * 64 + n]);
        }
    }
}

// ---------------- fused MLP v2: frag-major LDS + 2-phase double-buffered staging ----------------
// 64 rows x 256 hidden per block; 4 waves. All As/Bs frag reads are lane-linear
// (conflict-free); next K-tile stages while current computes (vmcnt drain lands
// after MFMA at the barrier).
__global__ __launch_bounds__(256, 2) void k_mlpf(
    const ushort* __restrict__ xb16, const float* __restrict__ action,
    const ushort* __restrict__ W1f, const ushort* __restrict__ W2f,
    const float* __restrict__ b1, const float* __restrict__ b2,
    const float* __restrict__ W3, float* __restrict__ out) {
    __shared__ __align__(16) ushort As[2][64 * 32];    //  8 KB (epilogue: red[64][4])
    __shared__ __align__(16) ushort Bs[2][256 * 32];   // 32 KB
    __shared__ __align__(16) ushort H1s[64 * H1P];     // 33 KB -> 74752 B, 2 blk/CU
    int tid = threadIdx.x;
    int w = tid >> 6, lane = tid & 63;
    int m0 = blockIdx.x * 64;
    int l15 = lane & 15, l4 = lane >> 4;

    // staging role: this thread stages the 16B chunk for (mt = tid>>6, lane = tid&63)
    int arow = (tid >> 6) * 16 + (tid & 15);   // tile-local row it stages
    int aseg = (tid >> 4) & 3;                 // k-subsegment (8 shorts)
    int gr = m0 + arow;
    int gb = gr / 100, grr = gr - gb * 100;
    const float* abp = action + (size_t)gb * 10000 + (size_t)grr * 100;

    float b1v[4], b2v[4], w3v[4];
    #pragma unroll
    for (int nt = 0; nt < 4; ++nt) {
        int col = w * 64 + nt * 16 + l15;
        b1v[nt] = b1[col];
        b2v[nt] = b2[col];
        w3v[nt] = W3[col];
    }

    f32x4 acc[4][4] = {};

    // ---- prologue: stage kt=0 ----
    #pragma unroll
    for (int i = 0; i < 4; ++i)
        gload16(W1f + ((size_t)(0 * 4 + i) * 256 + tid) * 8, (char*)Bs[0] + i * 4096 + tid * 16);
    gload16(xb16 + (size_t)gr * 64 + 0 * 32 + aseg * 8, (char*)As[0] + tid * 16);
    __syncthreads();

    int cur = 0;
    // ---- phase 1: h1 = relu(concat(x,action) @ W1^T + b1), K=192 ----
    for (int kt = 0; kt < 6; ++kt) {
        int nxt = cur ^ 1;
        if (kt < 5) {
            #pragma unroll
            for (int i = 0; i < 4; ++i)
                gload16(W1f + ((size_t)((kt + 1) * 4 + i) * 256 + tid) * 8,
                        (char*)Bs[nxt] + i * 4096 + tid * 16);
            if (kt + 1 < 2) {
                gload16(xb16 + (size_t)gr * 64 + (kt + 1) * 32 + aseg * 8,
                        (char*)As[nxt] + tid * 16);
            } else {
                int c0 = (kt + 1) * 32 - 64 + aseg * 8;
                ushort tmp[8];
                #pragma unroll
                for (int u = 0; u < 8; ++u) {
                    int cc = c0 + u;
                    tmp[u] = (cc < NR) ? f2bf(abp[cc]) : (ushort)0;
                }
                *(short8*)((char*)As[nxt] + tid * 16) = *(const short8*)tmp;
            }
        } else {
            // prefetch phase-2 first W2 tile
            #pragma unroll
            for (int i = 0; i < 4; ++i)
                gload16(W2f + ((size_t)(0 * 4 + i) * 256 + tid) * 8,
                        (char*)Bs[nxt] + i * 4096 + tid * 16);
        }
        short8 af[4], bf[4];
        #pragma unroll
        for (int mt = 0; mt < 4; ++mt)
            af[mt] = *(const short8*)((const char*)As[cur] + mt * 1024 + lane * 16);
        #pragma unroll
        for (int nt = 0; nt < 4; ++nt)
            bf[nt] = *(const short8*)((const char*)Bs[cur] + w * 4096 + nt * 1024 + lane * 16);
        #pragma unroll
        for (int mt = 0; mt < 4; ++mt)
            #pragma unroll
            for (int nt = 0; nt < 4; ++nt)
                acc[mt][nt] = __builtin_amdgcn_mfma_f32_16x16x32_bf16(
                    af[mt], bf[nt], acc[mt][nt], 0, 0, 0);
        if (kt == 5) {
            // h1 tile -> H1s (bf16, relu+bias)
            #pragma unroll
            for (int mt = 0; mt < 4; ++mt)
                #pragma unroll
                for (int nt = 0; nt < 4; ++nt) {
                    int col = w * 64 + nt * 16 + l15;
                    #pragma unroll
                    for (int r = 0; r < 4; ++r) {
                        int row = mt * 16 + l4 * 4 + r;
                        H1s[row * H1P + col] = f2bf(fmaxf(acc[mt][nt][r] + b1v[nt], 0.f));
                    }
                }
        }
        __syncthreads();
        cur = nxt;
    }

    #pragma unroll
    for (int mt = 0; mt < 4; ++mt)
        #pragma unroll
        for (int nt = 0; nt < 4; ++nt)
            acc[mt][nt] = (f32x4){0.f, 0.f, 0.f, 0.f};

    // ---- phase 2: h2 = relu(H1 @ W2^T + b2), K=256 ----
    for (int kt = 0; kt < 8; ++kt) {
        int nxt = cur ^ 1;
        if (kt < 7) {
            #pragma unroll
            for (int i = 0; i < 4; ++i)
                gload16(W2f + ((size_t)((kt + 1) * 4 + i) * 256 + tid) * 8,
                        (char*)Bs[nxt] + i * 4096 + tid * 16);
        }
        int k0 = kt * 32;
        short8 af[4], bf[4];
        #pragma unroll
        for (int mt = 0; mt < 4; ++mt)
            af[mt] = *(const short8*)((const char*)H1s +
                     ((size_t)(mt * 16 + l15) * H1P + k0 + l4 * 8) * 2);
        #pragma unroll
        for (int nt = 0; nt < 4; ++nt)
            bf[nt] = *(const short8*)((const char*)Bs[cur] + w * 4096 + nt * 1024 + lane * 16);
        #pragma unroll
        for (int mt = 0; mt < 4; ++mt)
            #pragma unroll
            for (int nt = 0; nt < 4; ++nt)
                acc[mt][nt] = __builtin_amdgcn_mfma_f32_16x16x32_bf16(
                    af[mt], bf[nt], acc[mt][nt], 0, 0, 0);
        __syncthreads();
        cur = nxt;
    }

    // ---- epilogue: relu + b2, xW3, row-sum, per-graph segmented reduce ----
    float* red = (float*)As;                  // [64 rows][4 waves]
    #pragma unroll
    for (int mt = 0; mt < 4; ++mt)
        #pragma unroll
        for (int r = 0; r < 4; ++r) {
            float v = 0.f;
            #pragma unroll
            for (int nt = 0; nt < 4; ++nt)
                v += fmaxf(acc[mt][nt][r] + b2v[nt], 0.f) * w3v[nt];
            v += __shfl_xor(v, 1);
            v += __shfl_xor(v, 2);
            v += __shfl_xor(v, 4);
            v += __shfl_xor(v, 8);
            if (l15 == 0) red[(mt * 16 + l4 * 4 + r) * 4 + w] = v;
        }
    __syncthreads();
    if (tid < 64) {
        float s = red[tid * 4 + 0] + red[tid * 4 + 1] + red[tid * 4 + 2] + red[tid * 4 + 3];
        int gbase = m0;
        int g0 = gbase / 100;
        int r0 = gbase - g0 * 100;
        int split = 100 - r0; if (split > 64) split = 64;
        float v0 = (tid < split) ? s : 0.f;
        float vs = s;
        #pragma unroll
        for (int d = 1; d < 64; d <<= 1) {
            v0 += __shfl_xor(v0, d);
            vs += __shfl_xor(vs, d);
        }
        if (tid == 0) {
            atomicAdd(&out[g0], v0);
            if (split < 64) atomicAdd(&out[g0 + 1], vs - v0);
        }
    }
}

__global__ void k_init_out(float* __restrict__ out, const float* __restrict__ b3) {
    int i = blockIdx.x * 256 + threadIdx.x;
    out[i] = b3[0];
}

// ---------------- launch ----------------

extern "C" void kernel_launch(void* const* d_in, const int* in_sizes, int n_in,
                              void* d_out, int out_size, void* d_ws, size_t ws_size,
                              hipStream_t stream) {
    const float* state  = (const float*)d_in[0];
    const int*   ei     = (const int*)d_in[1];
    const float* action = (const float*)d_in[2];
    const float* Wg     = (const float*)d_in[3];
    const float* bg     = (const float*)d_in[4];
    const float* W1     = (const float*)d_in[5];
    const float* b1     = (const float*)d_in[6];
    const float* W2     = (const float*)d_in[7];
    const float* b2     = (const float*)d_in[8];
    const float* W3     = (const float*)d_in[9];
    const float* b3     = (const float*)d_in[10];
    float* out = (float*)d_out;

    char* ws = (char*)d_ws;
    // Overlays (live ranges):
    //   [0, 13.1MB)     part (bscat..sortb)
    //   [13.1, 39.3)    ssb32 (ssb..gcn)
    //   [39.3, 65.5)    xb16 (gcn..mlpf)
    //   [65.5, 78.6)    csr (sortb..gcn)
    uint32* part  = (uint32*)(ws + 0);                 // 13,107,200
    uint32* ssb32 = (uint32*)(ws + 13107200);          // 26,214,400
    ushort* xb16  = (ushort*)(ws + 39321600);          // 26,214,400
    int*   csr    = (int*)  (ws + 65536000);           // 13,107,200
    int*   cnt    = (int*)  (ws + 78643200);           //    819,200
    int*   offs   = (int*)  (ws + 79462400);           //    819,200
    float* dinv   = (float*)(ws + 80281600);           //    819,200
    int*   bcnt   = (int*)  (ws + 81100800);           //      1,600
    int*   boffs  = (int*)  (ws + 81102400);           //      1,600
    int*   bcur   = (int*)  (ws + 81104000);           //      1,600
    ushort* W1f   = (ushort*)(ws + 81105600);          //     98,304
    ushort* W2f   = (ushort*)(ws + 81203904);          //    131,072
    ushort* Wgt   = (ushort*)(ws + 81334976);          //      8,192 -> end 81,343,168

    hipMemsetAsync(bcnt, 0, NBKT * sizeof(int), stream);
    k_init_out<<<NB / 256, 256, 0, stream>>>(out, b3);

    k_bhist<<<N_EDGES / 2048, 256, 0, stream>>>(ei, bcnt);
    k_bscan<<<1, 512, 0, stream>>>(bcnt, boffs, bcur);
    k_bscat<<<N_EDGES / 2048, 256, 0, stream>>>(ei, bcur, part);
    k_sortb<<<NBKT, 512, 0, stream>>>(part, boffs, bcnt, csr, cnt, offs, dinv);
    k_ssb<<<(N_NODES * 32) / 256, 256, 0, stream>>>(state, dinv, ssb32);
    k_packW<<<(49152 + 65536 + 4096 + 255) / 256, 256, 0, stream>>>(
        W1, W2, Wg, W1f, W2f, Wgt);
    k_gcn<<<N_NODES / 32, 256, 0, stream>>>(ssb32, state, csr, offs, cnt, dinv,
                                            Wgt, bg, xb16);
    k_mlpf<<<N_NODES / 64, 256, 0, stream>>>(xb16, action, W1f, W2f, b1, b2, W3, out);
}

// Round 10
// 303.008 us; speedup vs baseline: 8.9784x; 1.0714x over previous
//
#include <hip/hip_runtime.h>
#include <hip/hip_bf16.h>
#include <cstdint>
#include <cstddef>

#define N_NODES 204800
#define N_EDGES 3276800
#define NB 2048
#define NR 100
#define NC 64
#define NH 256
#define KPAD 192          // 64 + 100 + bias(1) padded to 192 (6 x K32 steps)
#define NBKT 400          // buckets of 512 dst nodes

typedef __attribute__((ext_vector_type(8))) short short8;
typedef __attribute__((ext_vector_type(4))) float f32x4;
typedef unsigned int uint32;

__device__ __forceinline__ void gload16(const void* g, void* l) {
    __builtin_amdgcn_global_load_lds(
        (const __attribute__((address_space(1))) uint32_t*)(g),
        (__attribute__((address_space(3))) uint32_t*)(l), 16, 0, 0);
}

__device__ __forceinline__ ushort f2bf(float v) {
    __hip_bfloat16 h = __float2bfloat16(v);
    return *reinterpret_cast<ushort*>(&h);
}

__device__ __forceinline__ uint32 pack2bf(float a, float b) {
    return (uint32)f2bf(a) | ((uint32)f2bf(b) << 16);
}

__device__ __forceinline__ float bflo(uint32 v) { return __uint_as_float(v << 16); }
__device__ __forceinline__ float bfhi(uint32 v) { return __uint_as_float(v & 0xFFFF0000u); }

// ---------------- bucket histogram ----------------

__global__ __launch_bounds__(256) void k_bhist(const int* __restrict__ ei,
                                               int* __restrict__ bcnt) {
    __shared__ int h[NBKT];
    int t = threadIdx.x;
    for (int i = t; i < NBKT; i += 256) h[i] = 0;
    __syncthreads();
    #pragma unroll 8
    for (int k = 0; k < 8; ++k) {
        int e = blockIdx.x * 2048 + k * 256 + t;
        atomicAdd(&h[ei[N_EDGES + e] >> 9], 1);
    }
    __syncthreads();
    for (int i = t; i < NBKT; i += 256)
        if (h[i]) atomicAdd(&bcnt[i], h[i]);
}

__global__ void k_bscan(const int* __restrict__ bcnt, int* __restrict__ boffs,
                        int* __restrict__ bcur) {
    __shared__ int tmp[512];
    int t = threadIdx.x;
    int v = (t < NBKT) ? bcnt[t] : 0;
    tmp[t] = v;
    __syncthreads();
    for (int off = 1; off < 512; off <<= 1) {
        int x = 0;
        if (t >= off) x = tmp[t - off];
        __syncthreads();
        tmp[t] += x;
        __syncthreads();
    }
    if (t < NBKT) {
        int o = tmp[t] - v;
        boffs[t] = o;
        bcur[t] = o;
    }
}

// radix partition: part[] gets src | (dlocal<<18), grouped by bucket
__global__ __launch_bounds__(256) void k_bscat(const int* __restrict__ ei,
                                               int* __restrict__ bcur,
                                               uint32* __restrict__ part) {
    __shared__ int hist[NBKT];
    int tid = threadIdx.x;
    for (int i = tid; i < NBKT; i += 256) hist[i] = 0;
    __syncthreads();

    uint32 w[8];
    int bk[8], r[8];
    #pragma unroll 8
    for (int k = 0; k < 8; ++k) {
        int e = blockIdx.x * 2048 + k * 256 + tid;
        int s = ei[e];
        int d = ei[N_EDGES + e];
        int b = d >> 9;
        w[k] = (uint32)s | ((uint32)(d & 511) << 18);
        bk[k] = b;
        r[k] = atomicAdd(&hist[b], 1);
    }
    __syncthreads();
    for (int i = tid; i < NBKT; i += 256) {
        int c = hist[i];
        hist[i] = c ? atomicAdd(&bcur[i], c) : 0;
    }
    __syncthreads();
    #pragma unroll 8
    for (int k = 0; k < 8; ++k)
        part[hist[bk[k]] + r[k]] = w[k];
}

// per-bucket counting sort -> CSR ; also emits cnt/offs/dinv
__global__ __launch_bounds__(512) void k_sortb(
    const uint32* __restrict__ part, const int* __restrict__ boffs,
    const int* __restrict__ bcnt, int* __restrict__ csr,
    int* __restrict__ cnt, int* __restrict__ offs, float* __restrict__ dinv) {
    __shared__ int h[512];
    __shared__ int cur[512];
    int b = blockIdx.x, t = threadIdx.x;
    h[t] = 0;
    __syncthreads();
    int base = boffs[b], n = bcnt[b];
    for (int i = t; i < n; i += 512)
        atomicAdd(&h[part[base + i] >> 18], 1);
    __syncthreads();
    int v = h[t];
    int node = b * 512 + t;
    cnt[node] = v;
    dinv[node] = rsqrtf((float)(v + 1));        // +1 self loop
    __syncthreads();
    for (int off = 1; off < 512; off <<= 1) {
        int x = 0;
        if (t >= off) x = h[t - off];
        __syncthreads();
        h[t] += x;
        __syncthreads();
    }
    int excl = h[t] - v;
    offs[node] = base + excl;
    cur[t] = excl;
    __syncthreads();
    for (int i = t; i < n; i += 512) {
        uint32 ew = part[base + i];
        int dl = ew >> 18;
        int pos = atomicAdd(&cur[dl], 1);
        csr[base + pos] = (int)(ew & 0x3FFFF);
    }
}

// ssb[i][c] = bf16(dinv[i] * state[i][c]), packed 2 channels per uint
__global__ void k_ssb(const float* __restrict__ state, const float* __restrict__ dinv,
                      uint32* __restrict__ ssb32) {
    int idx = blockIdx.x * 256 + threadIdx.x;
    int row = idx >> 5;
    float d = dinv[row];
    float2 v = reinterpret_cast<const float2*>(state)[idx];
    ssb32[idx] = pack2bf(v.x * d, v.y * d);
}

// ---------------- GCN: dual-row gather (unroll 8) + MFMA xW + relu + residual ----------------
__global__ __launch_bounds__(256) void k_gcn(
    const uint32* __restrict__ ssb32, const float* __restrict__ state,
    const int* __restrict__ csr, const int* __restrict__ offs,
    const int* __restrict__ cnt, const float* __restrict__ dinv,
    const ushort* __restrict__ Wgt, const float* __restrict__ bg,
    ushort* __restrict__ xb16) {
    __shared__ uint32 av[32 * 36];     // [32 rows][36 dwords] (72-short pitch)
    __shared__ ushort wgs[64 * 72];    // Wg^T padded: [n][72]
    int tid = threadIdx.x;
    int w = tid >> 6, lane = tid & 63;
    int half = lane >> 5, l = lane & 31;
    int R0 = blockIdx.x * 32;

    // stage Wg^T (bf16, n-major) -> padded LDS
    {
        int r = tid >> 2, c0 = (tid & 3) * 16;
        short8 v0 = *(const short8*)(Wgt + r * 64 + c0);
        short8 v1 = *(const short8*)(Wgt + r * 64 + c0 + 8);
        *(short8*)(wgs + r * 72 + c0) = v0;
        *(short8*)(wgs + r * 72 + c0 + 8) = v1;
    }

    for (int rr = 0; rr < 4; ++rr) {
        int lrow = w * 8 + rr * 2 + half;
        int row = R0 + lrow;
        float di = dinv[row];
        float2 st2 = *reinterpret_cast<const float2*>(state + (size_t)row * 64 + 2 * l);
        int s0 = offs[row], c = cnt[row];
        float x0 = 0.f, y0 = 0.f, x1 = 0.f, y1 = 0.f;
        float x2 = 0.f, y2 = 0.f, x3 = 0.f, y3 = 0.f;
        int e = 0;
        for (; e + 8 <= c; e += 8) {
            int sa = csr[s0 + e + 0];
            int sb = csr[s0 + e + 1];
            int sc = csr[s0 + e + 2];
            int sd = csr[s0 + e + 3];
            int se = csr[s0 + e + 4];
            int sf = csr[s0 + e + 5];
            int sg = csr[s0 + e + 6];
            int sh = csr[s0 + e + 7];
            uint32 va = ssb32[(size_t)sa * 32 + l];
            uint32 vb = ssb32[(size_t)sb * 32 + l];
            uint32 vc = ssb32[(size_t)sc * 32 + l];
            uint32 vd = ssb32[(size_t)sd * 32 + l];
            uint32 ve = ssb32[(size_t)se * 32 + l];
            uint32 vf = ssb32[(size_t)sf * 32 + l];
            uint32 vg = ssb32[(size_t)sg * 32 + l];
            uint32 vh = ssb32[(size_t)sh * 32 + l];
            x0 += bflo(va); y0 += bfhi(va);
            x1 += bflo(vb); y1 += bfhi(vb);
            x2 += bflo(vc); y2 += bfhi(vc);
            x3 += bflo(vd); y3 += bfhi(vd);
            x0 += bflo(ve); y0 += bfhi(ve);
            x1 += bflo(vf); y1 += bfhi(vf);
            x2 += bflo(vg); y2 += bfhi(vg);
            x3 += bflo(vh); y3 += bfhi(vh);
        }
        for (; e + 4 <= c; e += 4) {
            int sa = csr[s0 + e + 0];
            int sb = csr[s0 + e + 1];
            int sc = csr[s0 + e + 2];
            int sd = csr[s0 + e + 3];
            uint32 va = ssb32[(size_t)sa * 32 + l];
            uint32 vb = ssb32[(size_t)sb * 32 + l];
            uint32 vc = ssb32[(size_t)sc * 32 + l];
            uint32 vd = ssb32[(size_t)sd * 32 + l];
            x0 += bflo(va); y0 += bfhi(va);
            x1 += bflo(vb); y1 += bfhi(vb);
            x2 += bflo(vc); y2 += bfhi(vc);
            x3 += bflo(vd); y3 += bfhi(vd);
        }
        for (; e < c; ++e) {
            int s = csr[s0 + e];
            uint32 v = ssb32[(size_t)s * 32 + l];
            x0 += bflo(v); y0 += bfhi(v);
        }
        float ax = ((x0 + x1) + (x2 + x3)) * di + di * di * st2.x;
        float ay = ((y0 + y1) + (y2 + y3)) * di + di * di * st2.y;
        av[lrow * 36 + l] = pack2bf(ax, ay);
    }
    __syncthreads();

    // MFMA: C = av(32x64) @ Wg(64x64); wave w owns cols w*16..+15
    int l15 = lane & 15, l4 = lane >> 4;
    const ushort* avs = (const ushort*)av;
    f32x4 acc[2] = {};
    #pragma unroll
    for (int kk = 0; kk < 2; ++kk) {
        short8 bf = *(const short8*)(wgs + (w * 16 + l15) * 72 + kk * 32 + l4 * 8);
        #pragma unroll
        for (int mt = 0; mt < 2; ++mt) {
            short8 af = *(const short8*)(avs + (mt * 16 + l15) * 72 + kk * 32 + l4 * 8);
            acc[mt] = __builtin_amdgcn_mfma_f32_16x16x32_bf16(af, bf, acc[mt], 0, 0, 0);
        }
    }
    int col = w * 16 + l15;
    float bgv = bg[col];
    #pragma unroll
    for (int mt = 0; mt < 2; ++mt)
        #pragma unroll
        for (int r = 0; r < 4; ++r) {
            int row = R0 + mt * 16 + l4 * 4 + r;
            float v = fmaxf(acc[mt][r] + bgv, 0.f) + state[(size_t)row * 64 + col];
            xb16[(size_t)row * 64 + col] = f2bf(v);
        }
}

// ---------------- pack weights: FRAGMENT-MAJOR ----------------
// chunk id = (kt*4+i)*256 + tid, tid = wp*64+l. Chunk short u:
//   k = kt*32 + (l>>4)*8 + u ;  j = i*64 + wp*16 + (l&15)
// W1f row k==164 carries b1 (bias folded into GEMM via constant-1 input).
__global__ void k_packW(const float* __restrict__ W1, const float* __restrict__ W2,
                        const float* __restrict__ Wg, const float* __restrict__ b1,
                        ushort* __restrict__ W1f, ushort* __restrict__ W2f,
                        ushort* __restrict__ Wgt) {
    int t = blockIdx.x * 256 + threadIdx.x;
    if (t < 6 * 4 * 256 * 8) {                      // W1f: 49152 shorts
        int u = t & 7, chunk = t >> 3;
        int tid = chunk & 255, ktI = chunk >> 8;
        int kt = ktI >> 2, i = ktI & 3;
        int l = tid & 63, wp = tid >> 6;
        int k = kt * 32 + (l >> 4) * 8 + u;
        int j = i * 64 + wp * 16 + (l & 15);
        ushort v = 0;
        if (k < NC + NR) v = f2bf(W1[(size_t)k * NH + j]);
        else if (k == NC + NR) v = f2bf(b1[j]);
        W1f[t] = v;
    } else if (t < 49152 + 8 * 4 * 256 * 8) {       // W2f: 65536 shorts
        int t2 = t - 49152;
        int u = t2 & 7, chunk = t2 >> 3;
        int tid = chunk & 255, ktI = chunk >> 8;
        int kt = ktI >> 2, i = ktI & 3;
        int l = tid & 63, wp = tid >> 6;
        int k = kt * 32 + (l >> 4) * 8 + u;
        int j = i * 64 + wp * 16 + (l & 15);
        W2f[t2] = f2bf(W2[(size_t)k * NH + j]);
    } else {
        int t3 = t - 49152 - 65536;
        if (t3 < 64 * 64) {
            int n = t3 >> 6, k = t3 & 63;
            Wgt[t3] = f2bf(Wg[(size_t)k * 64 + n]);
        }
    }
}

// ---------------- fused MLP v3: register-resident H1, weights-only LDS ----------------
// 64 rows/block, wave w owns rows w*16..+15 (all 256 cols). Phase 1 computes
// D = mfma(W1_frag, x_frag) -> lane holds H1[row=lane&15][j=16jt+4g+r] (g=lane>>4).
// Phase 2 rebuilds A-fragments via a fixed 4-lane permutation (shfl), no LDS H1.
__global__ __launch_bounds__(256, 3) void k_mlpf(
    const ushort* __restrict__ xb16, const float* __restrict__ action,
    const ushort* __restrict__ W1f, const ushort* __restrict__ W2f,
    const float* __restrict__ b2, const float* __restrict__ W3,
    float* __restrict__ out) {
    __shared__ __align__(16) ushort Bs[2][256 * 32];   // 32 KB total
    int tid = threadIdx.x;
    int w = tid >> 6, lane = tid & 63;
    int s = lane & 15, g = lane >> 4;
    int m0 = blockIdx.x * 64;
    int myrow = m0 + w * 16 + s;
    int gb = myrow / 100, grr = myrow - gb * 100;
    const float* abp = action + (size_t)gb * 10000 + (size_t)grr * 100;

    // x fragments for kt=0,1 (registers; per-lane 16B loads, L2-resident)
    short8 xf0 = *(const short8*)(xb16 + (size_t)myrow * 64 + g * 8);
    short8 xf1 = *(const short8*)(xb16 + (size_t)myrow * 64 + 32 + g * 8);

    // prologue: stage W1 kt=0
    #pragma unroll
    for (int i = 0; i < 4; ++i)
        gload16(W1f + ((size_t)(0 * 4 + i) * 256 + tid) * 8,
                (char*)Bs[0] + i * 4096 + tid * 16);
    __syncthreads();

    f32x4 acc1[16] = {};
    float4 pa0 = {0.f, 0.f, 0.f, 0.f}, pa1 = {0.f, 0.f, 0.f, 0.f};
    int cur = 0;

    // ---- phase 1: H1 = relu(W1^T-mfma), K=192 (k=164 is the bias-1 slot) ----
    #pragma unroll
    for (int kt = 0; kt < 6; ++kt) {
        int nxt = cur ^ 1;
        // build bf (x operand) for this kt from registers
        short8 bf;
        if (kt == 0) bf = xf0;
        else if (kt == 1) bf = xf1;
        else if (kt < 5) {
            ushort tm[8];
            tm[0] = f2bf(pa0.x); tm[1] = f2bf(pa0.y); tm[2] = f2bf(pa0.z); tm[3] = f2bf(pa0.w);
            tm[4] = f2bf(pa1.x); tm[5] = f2bf(pa1.y); tm[6] = f2bf(pa1.z); tm[7] = f2bf(pa1.w);
            bf = *(const short8*)tm;
        } else {  // kt==5: cc = 96+g*8+u ; cc<100 action, cc==100 bias-1, else 0
            ushort tm[8];
            if (g == 0) {
                tm[0] = f2bf(pa0.x); tm[1] = f2bf(pa0.y); tm[2] = f2bf(pa0.z); tm[3] = f2bf(pa0.w);
                tm[4] = (ushort)0x3F80; tm[5] = 0; tm[6] = 0; tm[7] = 0;
            } else {
                #pragma unroll
                for (int u = 0; u < 8; ++u) tm[u] = 0;
            }
            bf = *(const short8*)tm;
        }
        // prefetch action regs for kt+1
        if (kt >= 1 && kt <= 3) {
            int c0 = (kt + 1) * 32 - 64 + g * 8;
            pa0 = *(const float4*)(abp + c0);
            pa1 = *(const float4*)(abp + c0 + 4);
        } else if (kt == 4) {
            if (g == 0) pa0 = *(const float4*)(abp + 96);
        }
        // stage next tile
        if (kt < 5) {
            #pragma unroll
            for (int i = 0; i < 4; ++i)
                gload16(W1f + ((size_t)((kt + 1) * 4 + i) * 256 + tid) * 8,
                        (char*)Bs[nxt] + i * 4096 + tid * 16);
        } else {
            #pragma unroll
            for (int i = 0; i < 4; ++i)
                gload16(W2f + ((size_t)(0 * 4 + i) * 256 + tid) * 8,
                        (char*)Bs[nxt] + i * 4096 + tid * 16);
        }
        // 16 MFMAs: af = W1 fragment for j-tile jt
        #pragma unroll
        for (int jt = 0; jt < 16; ++jt) {
            short8 af = *(const short8*)((const char*)Bs[cur] +
                         (jt >> 2) * 4096 + (jt & 3) * 1024 + lane * 16);
            acc1[jt] = __builtin_amdgcn_mfma_f32_16x16x32_bf16(af, bf, acc1[jt], 0, 0, 0);
        }
        __syncthreads();
        cur = nxt;
    }

    // relu + pack H1 to bf16 pairs: q0[jt]=(r0,r1), q1[jt]=(r2,r3)
    uint32 q0[16], q1[16];
    #pragma unroll
    for (int jt = 0; jt < 16; ++jt) {
        q0[jt] = pack2bf(fmaxf(acc1[jt][0], 0.f), fmaxf(acc1[jt][1], 0.f));
        q1[jt] = pack2bf(fmaxf(acc1[jt][2], 0.f), fmaxf(acc1[jt][3], 0.f));
    }

    // ---- phase 2: h2 = relu(H1 @ W2^T + b2), K=256; A from register shuffles ----
    f32x4 acc2[16] = {};
    int src0 = ((lane & 16) << 1) | s;   // lane 16*(2*(g&1)) + s
    int src1 = src0 + 16;
    bool hiSel = (lane & 32) != 0;       // g>=2 -> needs jt=2kt+1
    #pragma unroll
    for (int kt = 0; kt < 8; ++kt) {
        int nxt = cur ^ 1;
        if (kt < 7) {
            #pragma unroll
            for (int i = 0; i < 4; ++i)
                gload16(W2f + ((size_t)((kt + 1) * 4 + i) * 256 + tid) * 8,
                        (char*)Bs[nxt] + i * 4096 + tid * 16);
        }
        // af assembly: k = 32kt + 8g + u ; source lanes 32*(g&1)+s (+16)
        uint32 al0 = (uint32)__shfl((int)q0[2 * kt],     src0);
        uint32 ah0 = (uint32)__shfl((int)q0[2 * kt + 1], src0);
        uint32 bl0 = (uint32)__shfl((int)q1[2 * kt],     src0);
        uint32 bh0 = (uint32)__shfl((int)q1[2 * kt + 1], src0);
        uint32 al1 = (uint32)__shfl((int)q0[2 * kt],     src1);
        uint32 ah1 = (uint32)__shfl((int)q0[2 * kt + 1], src1);
        uint32 bl1 = (uint32)__shfl((int)q1[2 * kt],     src1);
        uint32 bh1 = (uint32)__shfl((int)q1[2 * kt + 1], src1);
        short8 af;
        uint32* afp = (uint32*)&af;
        afp[0] = hiSel ? ah0 : al0;
        afp[1] = hiSel ? bh0 : bl0;
        afp[2] = hiSel ? ah1 : al1;
        afp[3] = hiSel ? bh1 : bl1;
        #pragma unroll
        for (int nt = 0; nt < 16; ++nt) {
            short8 bf = *(const short8*)((const char*)Bs[cur] +
                         (nt >> 2) * 4096 + (nt & 3) * 1024 + lane * 16);
            acc2[nt] = __builtin_amdgcn_mfma_f32_16x16x32_bf16(af, bf, acc2[nt], 0, 0, 0);
        }
        __syncthreads();
        cur = nxt;
    }

    // ---- epilogue: relu+b2, xW3, row-sum (over j2 lanes), per-graph reduce ----
    float vsum[4] = {0.f, 0.f, 0.f, 0.f};
    #pragma unroll
    for (int nt = 0; nt < 16; ++nt) {
        float b2v = b2[nt * 16 + s];
        float w3v = W3[nt * 16 + s];
        #pragma unroll
        for (int r = 0; r < 4; ++r)
            vsum[r] += fmaxf(acc2[nt][r] + b2v, 0.f) * w3v;
    }
    float* red = (float*)Bs;             // 64 f32 (Bs dead now)
    #pragma unroll
    for (int r = 0; r < 4; ++r) {
        float v = vsum[r];
        v += __shfl_xor(v, 1);
        v += __shfl_xor(v, 2);
        v += __shfl_xor(v, 4);
        v += __shfl_xor(v, 8);
        if (s == 0) red[w * 16 + g * 4 + r] = v;
    }
    __syncthreads();
    if (tid < 64) {
        float sv = red[tid];
        int gbase = m0;
        int g0 = gbase / 100;
        int r0 = gbase - g0 * 100;
        int split = 100 - r0; if (split > 64) split = 64;
        float v0 = (tid < split) ? sv : 0.f;
        float vs = sv;
        #pragma unroll
        for (int d = 1; d < 64; d <<= 1) {
            v0 += __shfl_xor(v0, d);
            vs += __shfl_xor(vs, d);
        }
        if (tid == 0) {
            atomicAdd(&out[g0], v0);
            if (split < 64) atomicAdd(&out[g0 + 1], vs - v0);
        }
    }
}

__global__ void k_init_out(float* __restrict__ out, const float* __restrict__ b3) {
    int i = blockIdx.x * 256 + threadIdx.x;
    out[i] = b3[0];
}

// ---------------- launch ----------------

extern "C" void kernel_launch(void* const* d_in, const int* in_sizes, int n_in,
                              void* d_out, int out_size, void* d_ws, size_t ws_size,
                              hipStream_t stream) {
    const float* state  = (const float*)d_in[0];
    const int*   ei     = (const int*)d_in[1];
    const float* action = (const float*)d_in[2];
    const float* Wg     = (const float*)d_in[3];
    const float* bg     = (const float*)d_in[4];
    const float* W1     = (const float*)d_in[5];
    const float* b1     = (const float*)d_in[6];
    const float* W2     = (const float*)d_in[7];
    const float* b2     = (const float*)d_in[8];
    const float* W3     = (const float*)d_in[9];
    const float* b3     = (const float*)d_in[10];
    float* out = (float*)d_out;

    char* ws = (char*)d_ws;
    uint32* part  = (uint32*)(ws + 0);                 // 13,107,200
    uint32* ssb32 = (uint32*)(ws + 13107200);          // 26,214,400
    ushort* xb16  = (ushort*)(ws + 39321600);          // 26,214,400
    int*   csr    = (int*)  (ws + 65536000);           // 13,107,200
    int*   cnt    = (int*)  (ws + 78643200);           //    819,200
    int*   offs   = (int*)  (ws + 79462400);           //    819,200
    float* dinv   = (float*)(ws + 80281600);           //    819,200
    int*   bcnt   = (int*)  (ws + 81100800);           //      1,600
    int*   boffs  = (int*)  (ws + 81102400);           //      1,600
    int*   bcur   = (int*)  (ws + 81104000);           //      1,600
    ushort* W1f   = (ushort*)(ws + 81105600);          //     98,304
    ushort* W2f   = (ushort*)(ws + 81203904);          //    131,072
    ushort* Wgt   = (ushort*)(ws + 81334976);          //      8,192 -> end 81,343,168

    hipMemsetAsync(bcnt, 0, NBKT * sizeof(int), stream);
    k_init_out<<<NB / 256, 256, 0, stream>>>(out, b3);

    k_bhist<<<N_EDGES / 2048, 256, 0, stream>>>(ei, bcnt);
    k_bscan<<<1, 512, 0, stream>>>(bcnt, boffs, bcur);
    k_bscat<<<N_EDGES / 2048, 256, 0, stream>>>(ei, bcur, part);
    k_sortb<<<NBKT, 512, 0, stream>>>(part, boffs, bcnt, csr, cnt, offs, dinv);
    k_ssb<<<(N_NODES * 32) / 256, 256, 0, stream>>>(state, dinv, ssb32);
    k_packW<<<(49152 + 65536 + 4096 + 255) / 256, 256, 0, stream>>>(
        W1, W2, Wg, b1, W1f, W2f, Wgt);
    k_gcn<<<N_NODES / 32, 256, 0, stream>>>(ssb32, state, csr, offs, cnt, dinv,
                                            Wgt, bg, xb16);
    k_mlpf<<<N_NODES / 64, 256, 0, stream>>>(xb16, action, W1f, W2f, b2, W3, out);
}